// Round 9
// baseline (143357.581 us; speedup 1.0000x reference)
//
#include <hip/hip_runtime.h>

#define B_ 128
#define T_ 256
#define H_ 512
#define O_ 256
#define X_ 768

typedef unsigned short u16;
typedef unsigned int u32;

#if __has_builtin(__builtin_amdgcn_exp2f)
#define EXP2(x) __builtin_amdgcn_exp2f(x)
#else
#define EXP2(x) exp2f(x)
#endif
#if __has_builtin(__builtin_amdgcn_rcpf)
#define RCPF(x) __builtin_amdgcn_rcpf(x)
#else
#define RCPF(x) (1.0f / (x))
#endif

#define LOG2E_F 1.4426950408889634f
#define TWOLOG2E_F 2.8853900817779268f

typedef __attribute__((ext_vector_type(8))) short short8;
typedef __attribute__((ext_vector_type(4))) float f32x4;

__device__ __forceinline__ float bf2f(u16 v) {
  union { u32 u; float f; } c; c.u = ((u32)v) << 16; return c.f;
}
__device__ __forceinline__ u16 f2bf(float f) {
  union { float f; u32 u; } c; c.f = f;
  return (u16)((c.u + 0x7FFFu + ((c.u >> 16) & 1u)) >> 16);
}
__device__ __forceinline__ float ftanh(float x) {
  x = fminf(fmaxf(x, -40.f), 40.f);
  float z = EXP2(x * TWOLOG2E_F);
  return (z - 1.0f) * RCPF(z + 1.0f);
}
__device__ __forceinline__ float fsigm(float x) {
  x = fminf(fmaxf(x, -40.f), 40.f);
  return RCPF(1.0f + EXP2(-x * LOG2E_F));
}

// ---- module-scope scratch ----
__device__ u16 g_hp[(size_t)B_ * T_ * H_];   // bf16 h_proj
__device__ u16 g_hb[(size_t)B_ * T_ * H_];   // bf16 copy of h
__device__ float g_s[B_ * H_];               // fp32 state
__device__ float g_u[B_ * H_];
__device__ float g_sp[B_ * H_];              // s @ We1_s + be1
__device__ float g_p[B_ * H_];               // [y2,y2,c] @ WP (+bh fold)

// composite-weight scratch (fp32, one-time)
__device__ float g_wcru[512 * 1024];         // Wy3 @ [Wxr_top | Wxu_top]
__device__ float g_wch[512 * 512];           // Wy3 @ Wxh_top
__device__ float g_bru[1024];                // br|bu + by3 @ Wx_top
__device__ float g_bh[512];                  // by3 @ Wxh_top

// Fragment-packed activation A buffer (bf16 hi + lo residual), NKT=96 k-tiles.
// col slabs: [0,512)=y2, [512,1024)=y2 dup, [1024,1536)=c, [1536,2048)=s,
//            [2048,2560)=r*s, [2560,3072)=y1
// idx = ((rt*96 + kt)*512) + ((kg*16 + r)*8) + j ; rt=b>>4, r=b&15,
// kt=col>>5, kg=(col>>3)&3, j=col&7
__device__ u16 g_ah[(size_t)8 * 96 * 512];
__device__ u16 g_al[(size_t)8 * 96 * 512];

// Fragment-packed bf16 weights: idx = ((ntile*NKT + kt)*512 + l*8 + j)
__device__ u16 Wy1p[(size_t)32 * 16 * 512];
__device__ u16 Wy2p[(size_t)32 * 16 * 512];
__device__ u16 Wy3p[(size_t)16 * 16 * 512];
__device__ u16 We1sp[(size_t)32 * 16 * 512];
// WRUp: N=1024 (r|u), K=2048: kt0-15=Wc_hi, 16-31=Wc_lo, 32-47=Wx_mid, 48-63=Wh
__device__ u16 WRUp[(size_t)64 * 64 * 512];
// WPp: N=512, K=1536: kt0-15=Wch_hi, 16-31=Wch_lo, 32-47=Wxh_mid
__device__ u16 WPp[(size_t)32 * 48 * 512];
// Whhp: N=512, K=512
__device__ u16 Whhp[(size_t)32 * 16 * 512];

__device__ u16 cby1[H_];
__device__ u16 cby2[H_];
__device__ u16 cby3[O_];
__device__ u16 cbe1[H_];
__device__ u16 cWe2[H_];

// ---- per-producer flag slots: plain release stores, no RMW ----
#define SSTR 4   // u32 stride (16B) between slots
__device__ __align__(256) u32 g_slots[8][128 * SSTR];
#define F_S 0
#define F_Y1 1
#define F_Y2 2
#define F_SP 3
#define F_C 4
#define F_RU 5
#define F_P 6

__device__ __forceinline__ void publishv(int f, int slot, u32 val) {
  __threadfence();
  __syncthreads();
  if (threadIdx.x == 0)
    __hip_atomic_store(&g_slots[f][slot * SSTR], val, __ATOMIC_RELEASE,
                       __HIP_MEMORY_SCOPE_AGENT);
}
// Wave-0 parallel poll; capped so a deadlock degrades to an absmax failure.
__device__ __forceinline__ void waitv(int f, int nprod, u32 tgt) {
  if (threadIdx.x < 64) {
    const int l = threadIdx.x;
    for (u32 it = 0; it < 200000u; ++it) {
      bool ok = true;
      for (int s = l; s < nprod; s += 64)
        ok &= (__hip_atomic_load(&g_slots[f][s * SSTR], __ATOMIC_ACQUIRE,
                                 __HIP_MEMORY_SCOPE_AGENT) >= tgt);
      if (__all(ok)) break;
      __builtin_amdgcn_s_sleep(2);
    }
  }
  __syncthreads();
  __threadfence();
}

__global__ void reset_flags() {
  for (int i = threadIdx.x; i < 8 * 128 * SSTR; i += 512)
    ((u32*)g_slots)[i] = 0u;
}

__device__ __forceinline__ void store_packed(int b, int col, float v) {
  u16 hi = f2bf(v);
  size_t idx = (((size_t)(b >> 4) * 96 + (col >> 5)) << 9) +
               ((((col >> 3) & 3) * 16 + (b & 15)) << 3) + (col & 7);
  g_ah[idx] = hi;
  g_al[idx] = f2bf(v - bf2f(hi));
}

#define DEF_CONV(NAME, ARR, N)                                     \
  __global__ void conv_##NAME(const float* __restrict__ s) {       \
    int i = blockIdx.x * 256 + threadIdx.x;                        \
    if (i < (N)) ARR[i] = f2bf(s[i]);                              \
  }

DEF_CONV(by1, cby1, H_)
DEF_CONV(by2, cby2, H_)
DEF_CONV(by3, cby3, O_)
DEF_CONV(be1, cbe1, H_)
DEF_CONV(We2, cWe2, H_)

__global__ void conv_h(const float* __restrict__ s) {
  size_t i = (size_t)blockIdx.x * 256 + threadIdx.x;
  g_hb[i] = f2bf(s[i]);
}

// ---- composite GEMM: C[MODE] = A(512x256,lda256) @ B(256x512,ldb512) ----
// MODE selects the __device__ destination INSIDE device code (host code must
// never take the address of a __device__ symbol — that was the r4-r7 abort).
template <int MODE>
__global__ void __launch_bounds__(256) fgemm_comp(const float* __restrict__ A,
                                                  const float* __restrict__ B) {
  float* C = (MODE == 0) ? g_wcru : (MODE == 1) ? (g_wcru + 512) : g_wch;
  const int ldc = (MODE == 2) ? 512 : 1024;
  __shared__ float Ast[32][72];
  __shared__ float Bs[32][72];
  const int tid = threadIdx.x;
  const int tx = tid & 15, ty = tid >> 4;
  const int n0 = blockIdx.x << 6;
  const int m0 = blockIdx.y << 6;
  float acc[4][4] = {};
  for (int k0 = 0; k0 < 256; k0 += 32) {
    {
      int row = tid >> 2, kq = (tid & 3) << 3;
      const float* src = A + (size_t)(m0 + row) * 256 + k0 + kq;
      float4 v0 = *(const float4*)src;
      float4 v1 = *(const float4*)(src + 4);
      Ast[kq + 0][row] = v0.x; Ast[kq + 1][row] = v0.y;
      Ast[kq + 2][row] = v0.z; Ast[kq + 3][row] = v0.w;
      Ast[kq + 4][row] = v1.x; Ast[kq + 5][row] = v1.y;
      Ast[kq + 6][row] = v1.z; Ast[kq + 7][row] = v1.w;
    }
    {
      int kr = tid >> 3, nq = (tid & 7) << 3;
      const float* src = B + (size_t)(k0 + kr) * 512 + n0 + nq;
      float4 v0 = *(const float4*)src;
      float4 v1 = *(const float4*)(src + 4);
      float* d = &Bs[kr][nq];
      d[0] = v0.x; d[1] = v0.y; d[2] = v0.z; d[3] = v0.w;
      d[4] = v1.x; d[5] = v1.y; d[6] = v1.z; d[7] = v1.w;
    }
    __syncthreads();
#pragma unroll
    for (int kk = 0; kk < 32; ++kk) {
      const float4 a4 = *(const float4*)&Ast[kk][ty << 2];
      const float4 b4 = *(const float4*)&Bs[kk][tx << 2];
      float av[4] = {a4.x, a4.y, a4.z, a4.w};
      float bv[4] = {b4.x, b4.y, b4.z, b4.w};
#pragma unroll
      for (int i = 0; i < 4; ++i)
#pragma unroll
        for (int j = 0; j < 4; ++j) acc[i][j] = fmaf(av[i], bv[j], acc[i][j]);
    }
    __syncthreads();
  }
#pragma unroll
  for (int i = 0; i < 4; ++i)
#pragma unroll
    for (int j = 0; j < 4; ++j)
      C[(size_t)(m0 + ty * 4 + i) * ldc + n0 + tx * 4 + j] = acc[i][j];
}

__global__ void bias_fold(const float* __restrict__ by3,
                          const float* __restrict__ Wxr,
                          const float* __restrict__ Wxu,
                          const float* __restrict__ br,
                          const float* __restrict__ bu,
                          const float* __restrict__ Wxh) {
  int n = blockIdx.x * 256 + threadIdx.x;
  if (n < 1024) {
    const float* W = (n < 512) ? Wxr : Wxu;
    int nn = n & 511;
    float acc = (n < 512) ? br[nn] : bu[nn];
    for (int k = 0; k < 256; ++k) acc += by3[k] * W[(size_t)k * 512 + nn];
    g_bru[n] = acc;
  } else if (n < 1536) {
    int nn = n - 1024;
    float acc = 0.f;
    for (int k = 0; k < 256; ++k) acc += by3[k] * Wxh[(size_t)k * 512 + nn];
    g_bh[nn] = acc;
  }
}

// ---- weight packers ----
#define DEF_PACKB(NAME, DST, NKT, SRCEXPR)                               \
  __global__ void NAME(const float* __restrict__ S0) {                   \
    int gid = blockIdx.x * 256 + threadIdx.x;                            \
    int l = gid & 63, kt = (gid >> 6) % (NKT);                           \
    int ntile = gid / (64 * (NKT));                                      \
    int n = ntile * 16 + (l & 15);                                       \
    __align__(16) u16 tmp[8];                                            \
    _Pragma("unroll")                                                    \
    for (int j = 0; j < 8; ++j) {                                        \
      int k = kt * 32 + ((l >> 4) << 3) + j;                             \
      tmp[j] = f2bf(SRCEXPR);                                            \
    }                                                                    \
    *(uint4*)(DST + (size_t)gid * 8) = *(const uint4*)tmp;               \
  }

DEF_PACKB(pack_Wy1, Wy1p, 16, S0[(size_t)k * 512 + n])
DEF_PACKB(pack_Wy2, Wy2p, 16, S0[(size_t)k * 512 + n])
DEF_PACKB(pack_Wy3, Wy3p, 16, S0[(size_t)k * 256 + n])
DEF_PACKB(pack_We1s, We1sp, 16, S0[(size_t)(512 + k) * 512 + n])

__global__ void pack_WRU(const float* __restrict__ Wxr, const float* __restrict__ Whr,
                         const float* __restrict__ Wxu, const float* __restrict__ Whu) {
  int gid = blockIdx.x * 256 + threadIdx.x;   // 64 ntile * 64 kt * 64 lanes
  int l = gid & 63, kt = (gid >> 6) & 63;
  int ntile = gid >> 12;
  int n = ntile * 16 + (l & 15);
  int nn = n & 511;
  __align__(16) u16 tmp[8];
#pragma unroll
  for (int j = 0; j < 8; ++j) {
    int k = kt * 32 + ((l >> 4) << 3) + j;   // 0..2047
    float v;
    if (k < 512) v = g_wcru[(size_t)k * 1024 + n];
    else if (k < 1024) {
      float x = g_wcru[(size_t)(k - 512) * 1024 + n];
      v = x - bf2f(f2bf(x));
    } else if (k < 1536) {
      v = (n < 512) ? Wxr[(size_t)(k - 1024 + 256) * 512 + nn]
                    : Wxu[(size_t)(k - 1024 + 256) * 512 + nn];
    } else {
      v = (n < 512) ? Whr[(size_t)(k - 1536) * 512 + nn]
                    : Whu[(size_t)(k - 1536) * 512 + nn];
    }
    tmp[j] = f2bf(v);
  }
  *(uint4*)(WRUp + (size_t)gid * 8) = *(const uint4*)tmp;
}

__global__ void pack_WP(const float* __restrict__ Wxh) {
  int gid = blockIdx.x * 256 + threadIdx.x;   // 32 ntile * 48 kt * 64 lanes
  int l = gid & 63, kt = (gid >> 6) % 48;
  int ntile = gid / (64 * 48);
  int n = ntile * 16 + (l & 15);
  __align__(16) u16 tmp[8];
#pragma unroll
  for (int j = 0; j < 8; ++j) {
    int k = kt * 32 + ((l >> 4) << 3) + j;   // 0..1535
    float v;
    if (k < 512) v = g_wch[(size_t)k * 512 + n];
    else if (k < 1024) {
      float x = g_wch[(size_t)(k - 512) * 512 + n];
      v = x - bf2f(f2bf(x));
    } else {
      v = Wxh[(size_t)(k - 1024 + 256) * 512 + n];
    }
    tmp[j] = f2bf(v);
  }
  *(uint4*)(WPp + (size_t)gid * 8) = *(const uint4*)tmp;
}

__global__ void pack_Whh(const float* __restrict__ Whh) {
  int gid = blockIdx.x * 256 + threadIdx.x;   // 32 ntile * 16 kt * 64 lanes
  int l = gid & 63, kt = (gid >> 6) & 15;
  int ntile = gid >> 10;
  int n = ntile * 16 + (l & 15);
  __align__(16) u16 tmp[8];
#pragma unroll
  for (int j = 0; j < 8; ++j) {
    int k = kt * 32 + ((l >> 4) << 3) + j;
    tmp[j] = f2bf(Whh[(size_t)k * 512 + n]);
  }
  *(uint4*)(Whhp + (size_t)gid * 8) = *(const uint4*)tmp;
}

__global__ void init_kernel(const float* __restrict__ s0) {
  int g = blockIdx.x * blockDim.x + threadIdx.x;
  if (g < B_ * H_) {
    float v = s0[g];
    g_s[g] = v;
    int b = g >> 9, n = g & 511;
    store_packed(b, 1536 + n, v);
  }
}

// ---- h_proj = h @ We1[:H]  (fp32 in, bf16 out) ----
__global__ void __launch_bounds__(256) hproj_kernel(const float* __restrict__ hh,
                                                    const float* __restrict__ We1) {
  __shared__ float Ast[32][72];
  __shared__ float Bs[32][72];
  const int tid = threadIdx.x;
  const int tx = tid & 15, ty = tid >> 4;
  const int n0 = blockIdx.x << 6;
  const int m0 = blockIdx.y << 6;
  float acc[4][4] = {};
  for (int k0 = 0; k0 < H_; k0 += 32) {
    {
      int row = tid >> 2, kq = (tid & 3) << 3;
      const float* src = hh + (size_t)(m0 + row) * H_ + k0 + kq;
      float4 v0 = *(const float4*)src;
      float4 v1 = *(const float4*)(src + 4);
      Ast[kq + 0][row] = v0.x; Ast[kq + 1][row] = v0.y;
      Ast[kq + 2][row] = v0.z; Ast[kq + 3][row] = v0.w;
      Ast[kq + 4][row] = v1.x; Ast[kq + 5][row] = v1.y;
      Ast[kq + 6][row] = v1.z; Ast[kq + 7][row] = v1.w;
    }
    {
      int kr = tid >> 3, nq = (tid & 7) << 3;
      const float* src = We1 + (size_t)(k0 + kr) * H_ + n0 + nq;
      float4 v0 = *(const float4*)src;
      float4 v1 = *(const float4*)(src + 4);
      float* d = &Bs[kr][nq];
      d[0] = v0.x; d[1] = v0.y; d[2] = v0.z; d[3] = v0.w;
      d[4] = v1.x; d[5] = v1.y; d[6] = v1.z; d[7] = v1.w;
    }
    __syncthreads();
#pragma unroll
    for (int kk = 0; kk < 32; ++kk) {
      const float4 a4 = *(const float4*)&Ast[kk][ty << 2];
      const float4 b4 = *(const float4*)&Bs[kk][tx << 2];
      float av[4] = {a4.x, a4.y, a4.z, a4.w};
      float bv[4] = {b4.x, b4.y, b4.z, b4.w};
#pragma unroll
      for (int i = 0; i < 4; ++i)
#pragma unroll
        for (int j = 0; j < 4; ++j) acc[i][j] = fmaf(av[i], bv[j], acc[i][j]);
    }
    __syncthreads();
  }
#pragma unroll
  for (int i = 0; i < 4; ++i) {
    u16* dst = g_hp + (size_t)(m0 + ty * 4 + i) * H_ + n0 + tx * 4;
    u32 w0 = (u32)f2bf(acc[i][0]) | ((u32)f2bf(acc[i][1]) << 16);
    u32 w1 = (u32)f2bf(acc[i][2]) | ((u32)f2bf(acc[i][3]) << 16);
    *(u32*)dst = w0;
    *(u32*)(dst + 2) = w1;
  }
}

#define FMA8(pk, sk, A)                                          \
  {                                                              \
    u32 ww0 = pk.x, ww1 = pk.y, ww2 = pk.z, ww3 = pk.w;          \
    A[0] = fmaf(sk, bf2f((u16)(ww0 & 0xffffu)), A[0]);           \
    A[1] = fmaf(sk, bf2f((u16)(ww0 >> 16)), A[1]);               \
    A[2] = fmaf(sk, bf2f((u16)(ww1 & 0xffffu)), A[2]);           \
    A[3] = fmaf(sk, bf2f((u16)(ww1 >> 16)), A[3]);               \
    A[4] = fmaf(sk, bf2f((u16)(ww2 & 0xffffu)), A[4]);           \
    A[5] = fmaf(sk, bf2f((u16)(ww2 >> 16)), A[5]);               \
    A[6] = fmaf(sk, bf2f((u16)(ww3 & 0xffffu)), A[6]);           \
    A[7] = fmaf(sk, bf2f((u16)(ww3 >> 16)), A[7]);               \
  }

// ---- GEMM core: M=16, N=64, 8-wave k-split, hi/lo A ----
template <int KTA0, int NKT_B, int KTW>
__device__ __forceinline__ void gemm_core(const u16* __restrict__ BP, int mt,
                                          int nb, int tid, float* smem) {
  const int l = tid & 63, w = tid >> 6;
  f32x4 acc0 = {0.f, 0.f, 0.f, 0.f}, acc1 = {0.f, 0.f, 0.f, 0.f};
  f32x4 acc2 = {0.f, 0.f, 0.f, 0.f}, acc3 = {0.f, 0.f, 0.f, 0.f};
  const size_t abase = (((size_t)mt * 96 + KTA0 + w * KTW) << 9) + l * 8;
#pragma unroll
  for (int kk = 0; kk < KTW; ++kk) {
    short8 ah = *(const short8*)(g_ah + abase + (size_t)kk * 512);
    short8 al = *(const short8*)(g_al + abase + (size_t)kk * 512);
    const size_t bbase =
        (((size_t)(nb * 4) * NKT_B + w * KTW + kk) << 9) + l * 8;
    short8 b0 = *(const short8*)(BP + bbase);
    short8 b1 = *(const short8*)(BP + bbase + ((size_t)NKT_B << 9));
    short8 b2 = *(const short8*)(BP + bbase + ((size_t)2 * NKT_B << 9));
    short8 b3 = *(const short8*)(BP + bbase + ((size_t)3 * NKT_B << 9));
    acc0 = __builtin_amdgcn_mfma_f32_16x16x32_bf16(ah, b0, acc0, 0, 0, 0);
    acc0 = __builtin_amdgcn_mfma_f32_16x16x32_bf16(al, b0, acc0, 0, 0, 0);
    acc1 = __builtin_amdgcn_mfma_f32_16x16x32_bf16(ah, b1, acc1, 0, 0, 0);
    acc1 = __builtin_amdgcn_mfma_f32_16x16x32_bf16(al, b1, acc1, 0, 0, 0);
    acc2 = __builtin_amdgcn_mfma_f32_16x16x32_bf16(ah, b2, acc2, 0, 0, 0);
    acc2 = __builtin_amdgcn_mfma_f32_16x16x32_bf16(al, b2, acc2, 0, 0, 0);
    acc3 = __builtin_amdgcn_mfma_f32_16x16x32_bf16(ah, b3, acc3, 0, 0, 0);
    acc3 = __builtin_amdgcn_mfma_f32_16x16x32_bf16(al, b3, acc3, 0, 0, 0);
  }
  float* pw = smem + w * 1024;
  const int r0 = (l >> 4) * 4, c0 = l & 15;
#pragma unroll
  for (int r = 0; r < 4; ++r) {
    pw[(r0 + r) * 64 + 0 + c0] = acc0[r];
    pw[(r0 + r) * 64 + 16 + c0] = acc1[r];
    pw[(r0 + r) * 64 + 32 + c0] = acc2[r];
    pw[(r0 + r) * 64 + 48 + c0] = acc3[r];
  }
  __syncthreads();
}

#define EPI_V(row, col)                                              \
  float v = 0.f;                                                     \
  _Pragma("unroll") for (int ww = 0; ww < 8; ++ww)                   \
      v += smem[ww * 1024 + (row) * 64 + (col)];

// ---- persistent step loop: 256 blocks, 3 specialized pipelines ----
__global__ void __launch_bounds__(512, 2) k_loop(float* __restrict__ out) {
  __shared__ __align__(16) float smem[8192];
  __shared__ float red[16];
  const int tid = threadIdx.x;
  const int bid = blockIdx.x;

  for (int t = 0; t < T_; ++t) {
    const u32 nxt = (u32)(t + 1);
    if (bid < 64) {
      // ======== pipeline 0: y1 -> y2 -> HC ========
      const int mt = bid >> 3, nb = bid & 7;
      waitv(F_S, 64, (u32)t);
      { // y1 = tanh(s@Wy1+by1) -> slab y1 (col 2560+)
        gemm_core<48, 16, 2>(Wy1p, mt, nb, tid, smem);
#pragma unroll
        for (int rep = 0; rep < 2; ++rep) {
          int idx = rep * 512 + tid, row = idx >> 6, col = idx & 63;
          EPI_V(row, col);
          int gb = mt * 16 + row, gc = nb * 64 + col;
          v += bf2f(cby1[gc]);
          store_packed(gb, 2560 + gc, ftanh(v));
        }
      }
      publishv(F_Y1, bid, nxt);
      waitv(F_Y1, 64, nxt);
      { // y2 = tanh(y1@Wy2+by2) -> slabs col 0+ and 512+ (dup)
        gemm_core<80, 16, 2>(Wy2p, mt, nb, tid, smem);
#pragma unroll
        for (int rep = 0; rep < 2; ++rep) {
          int idx = rep * 512 + tid, row = idx >> 6, col = idx & 63;
          EPI_V(row, col);
          int gb = mt * 16 + row, gc = nb * 64 + col;
          v += bf2f(cby2[gc]);
          float y2v = ftanh(v);
          store_packed(gb, gc, y2v);
          store_packed(gb, 512 + gc, y2v);
        }
      }
      publishv(F_Y2, bid, nxt);
      waitv(F_RU, 128, nxt);
      waitv(F_P, 64, nxt);
      { // HC = tanh(g_p + rs@Whh); s update -> g_s + slab s (col 1536+)
        gemm_core<64, 16, 2>(Whhp, mt, nb, tid, smem);
#pragma unroll
        for (int rep = 0; rep < 2; ++rep) {
          int idx = rep * 512 + tid, row = idx >> 6, col = idx & 63;
          EPI_V(row, col);
          int gb = mt * 16 + row, gc = nb * 64 + col;
          int sidx = gb * H_ + gc;
          v += g_p[sidx];
          float hc = ftanh(v);
          float uu = g_u[sidx];
          float sn = (1.f - uu) * hc + uu * g_s[sidx];
          g_s[sidx] = sn;
          store_packed(gb, 1536 + gc, sn);
        }
      }
      publishv(F_S, bid, nxt);
    } else if (bid < 128) {
      // ======== pipeline 1: sp -> y3out -> P ========
      const int blk2 = bid - 64;
      const int mt = blk2 >> 3, nb = blk2 & 7;
      waitv(F_S, 64, (u32)t);
      { // sp = s@We1_s + be1
        gemm_core<48, 16, 2>(We1sp, mt, nb, tid, smem);
#pragma unroll
        for (int rep = 0; rep < 2; ++rep) {
          int idx = rep * 512 + tid, row = idx >> 6, col = idx & 63;
          EPI_V(row, col);
          int gb = mt * 16 + row, gc = nb * 64 + col;
          g_sp[gb * H_ + gc] = v + bf2f(cbe1[gc]);
        }
      }
      publishv(F_SP, blk2, nxt);
      waitv(F_Y2, 64, nxt);
      if (blk2 < 32) { // y3 -> out only
        const int mt3 = blk2 >> 2, nb3 = blk2 & 3;
        gemm_core<0, 16, 2>(Wy3p, mt3, nb3, tid, smem);
#pragma unroll
        for (int rep = 0; rep < 2; ++rep) {
          int idx = rep * 512 + tid, row = idx >> 6, col = idx & 63;
          EPI_V(row, col);
          int gb = mt3 * 16 + row, gc = nb3 * 64 + col;
          v += bf2f(cby3[gc]);
          out[((size_t)gb * T_ + t) * O_ + gc] = v;
        }
      }
      waitv(F_C, 128, nxt);
      { // P = [y2,y2,c] @ WP + bh
        gemm_core<0, 48, 6>(WPp, mt, nb, tid, smem);
#pragma unroll
        for (int rep = 0; rep < 2; ++rep) {
          int idx = rep * 512 + tid, row = idx >> 6, col = idx & 63;
          EPI_V(row, col);
          int gb = mt * 16 + row, gc = nb * 64 + col;
          g_p[gb * H_ + gc] = v + g_bh[gc];
        }
      }
      publishv(F_P, blk2, nxt);
    } else {
      // ======== pipeline 2: attn -> RU ========
      const int b = bid - 128;
      waitv(F_SP, 64, nxt);
      { // attention for batch row b
        float* sm_e = smem + 1024;
        {
          float spv = g_sp[b * H_ + tid];
          float w2 = bf2f(cWe2[tid]);
          smem[2 * tid] = spv * TWOLOG2E_F;
          smem[2 * tid + 1] = -2.0f * w2;
        }
        __syncthreads();
        const int wv = tid >> 6, l = tid & 63;
        const int rr = l & 15, q = l >> 4;
#pragma unroll
        for (int p = 0; p < 2; ++p) {
          int tp = p * 128 + wv * 16 + rr;
          const u16* rowp = g_hp + ((size_t)(b * T_ + tp) << 9);
          float part = 0.f;
          for (int i = 0; i < 16; ++i) {
            int c0 = i * 32 + q * 8;
            uint4 pk = *(const uint4*)(rowp + c0);
            const float4* swp = reinterpret_cast<const float4*>(smem + 2 * c0);
            float4 f0 = swp[0], f1 = swp[1], f2 = swp[2], f3 = swp[3];
            u32 ww[4] = {pk.x, pk.y, pk.z, pk.w};
            {
              float h0 = bf2f((u16)(ww[0] & 0xffffu)), h1 = bf2f((u16)(ww[0] >> 16));
              float x0 = fmaf(h0, TWOLOG2E_F, f0.x);
              float x1 = fmaf(h1, TWOLOG2E_F, f0.z);
              part = fmaf(f0.y, RCPF(EXP2(x0) + 1.f), part);
              part = fmaf(f0.w, RCPF(EXP2(x1) + 1.f), part);
            }
            {
              float h0 = bf2f((u16)(ww[1] & 0xffffu)), h1 = bf2f((u16)(ww[1] >> 16));
              float x0 = fmaf(h0, TWOLOG2E_F, f1.x);
              float x1 = fmaf(h1, TWOLOG2E_F, f1.z);
              part = fmaf(f1.y, RCPF(EXP2(x0) + 1.f), part);
              part = fmaf(f1.w, RCPF(EXP2(x1) + 1.f), part);
            }
            {
              float h0 = bf2f((u16)(ww[2] & 0xffffu)), h1 = bf2f((u16)(ww[2] >> 16));
              float x0 = fmaf(h0, TWOLOG2E_F, f2.x);
              float x1 = fmaf(h1, TWOLOG2E_F, f2.z);
              part = fmaf(f2.y, RCPF(EXP2(x0) + 1.f), part);
              part = fmaf(f2.w, RCPF(EXP2(x1) + 1.f), part);
            }
            {
              float h0 = bf2f((u16)(ww[3] & 0xffffu)), h1 = bf2f((u16)(ww[3] >> 16));
              float x0 = fmaf(h0, TWOLOG2E_F, f3.x);
              float x1 = fmaf(h1, TWOLOG2E_F, f3.z);
              part = fmaf(f3.y, RCPF(EXP2(x0) + 1.f), part);
              part = fmaf(f3.w, RCPF(EXP2(x1) + 1.f), part);
            }
          }
          part += __shfl_xor(part, 16, 64);
          part += __shfl_xor(part, 32, 64);
          if (q == 0) sm_e[tp] = part;
        }
        __syncthreads();
        float v = (tid < T_) ? sm_e[tid] : -3.0e38f;
        float m = v;
#pragma unroll
        for (int off = 32; off > 0; off >>= 1) m = fmaxf(m, __shfl_xor(m, off, 64));
        if (l == 0) red[wv] = m;
        __syncthreads();
        m = fmaxf(fmaxf(fmaxf(red[0], red[1]), fmaxf(red[2], red[3])),
                  fmaxf(fmaxf(red[4], red[5]), fmaxf(red[6], red[7])));
        float pe = (tid < T_) ? EXP2((v - m) * LOG2E_F) : 0.f;
        float ssum = pe;
#pragma unroll
        for (int off = 32; off > 0; off >>= 1) ssum += __shfl_xor(ssum, off, 64);
        if (l == 0) red[8 + wv] = ssum;
        __syncthreads();
        float tot = (red[8] + red[9]) + (red[10] + red[11]) +
                    (red[12] + red[13]) + (red[14] + red[15]);
        float ainv = RCPF(tot);
        if (tid < T_) sm_e[tid] = pe * ainv;
        __syncthreads();
        { // c = a @ h -> slab c (col 1024+)
          const int ts = tid >> 6, c = tid & 63, n0 = c << 3;
          float a[8] = {};
          for (int tp = ts * 32; tp < ts * 32 + 32; ++tp) {
            uint4 pk = *(const uint4*)(g_hb + ((size_t)(b * T_ + tp) << 9) + n0);
            float av = sm_e[tp];
            FMA8(pk, av, a);
          }
          float* pt = smem + 1536 + ts * 512 + n0;
#pragma unroll
          for (int j = 0; j < 8; ++j) pt[j] = a[j];
        }
        __syncthreads();
        {
          float v2 = 0.f;
#pragma unroll
          for (int kk = 0; kk < 8; ++kk) v2 += smem[1536 + kk * 512 + tid];
          store_packed(b, 1024 + tid, v2);
        }
      }
      publishv(F_C, b, nxt);
      waitv(F_C, 128, nxt);
      waitv(F_Y2, 64, nxt);
      const int mt = b >> 4, nbz = b & 15;
      { // RU = sigm([y2,y2,c,s]@WRU + bru) -> rs slab (col 2048+), u
        gemm_core<0, 64, 8>(WRUp, mt, nbz, tid, smem);
#pragma unroll
        for (int rep = 0; rep < 2; ++rep) {
          int idx = rep * 512 + tid, row = idx >> 6, col = idx & 63;
          EPI_V(row, col);
          int gb = mt * 16 + row, gc = nbz * 64 + col;
          v += g_bru[gc];
          if (gc < 512) {
            float rv = fsigm(v);
            float rs = rv * g_s[gb * H_ + gc];
            store_packed(gb, 2048 + gc, rs);
          } else {
            g_u[gb * H_ + (gc - 512)] = fsigm(v);
          }
        }
      }
      publishv(F_RU, b, nxt);
    }
  }
}

extern "C" void kernel_launch(void* const* d_in, const int* in_sizes, int n_in,
                              void* d_out, int out_size, void* d_ws, size_t ws_size,
                              hipStream_t stream) {
  (void)in_sizes; (void)n_in; (void)out_size; (void)d_ws; (void)ws_size;
  const float* h = (const float*)d_in[0];
  float* out = (float*)d_out;

  hipLaunchKernelGGL(reset_flags, dim3(1), dim3(512), 0, stream);
#define CONV(NAME, IDX, N) \
  hipLaunchKernelGGL(conv_##NAME, dim3(((N) + 255) / 256), dim3(256), 0, stream, \
                     (const float*)d_in[IDX])
  CONV(by1, 3, H_);
  CONV(by2, 5, H_);
  CONV(by3, 7, O_);
  CONV(be1, 9, H_);
  CONV(We2, 10, H_);
  // d_in[11] = be2: softmax shift-invariant, unused
#undef CONV
  // composite weights: destinations selected in device code (never pass
  // __device__ symbols as host-side kernel args — r4-r7 abort cause)
  hipLaunchKernelGGL((fgemm_comp<0>), dim3(8, 8), dim3(256), 0, stream,
                     (const float*)d_in[6], (const float*)d_in[12]);
  hipLaunchKernelGGL((fgemm_comp<1>), dim3(8, 8), dim3(256), 0, stream,
                     (const float*)d_in[6], (const float*)d_in[15]);
  hipLaunchKernelGGL((fgemm_comp<2>), dim3(8, 8), dim3(256), 0, stream,
                     (const float*)d_in[6], (const float*)d_in[18]);
  hipLaunchKernelGGL(bias_fold, dim3(6), dim3(256), 0, stream,
                     (const float*)d_in[7], (const float*)d_in[12],
                     (const float*)d_in[15], (const float*)d_in[14],
                     (const float*)d_in[17], (const float*)d_in[18]);
  hipLaunchKernelGGL(pack_Wy1, dim3(128), dim3(256), 0, stream, (const float*)d_in[2]);
  hipLaunchKernelGGL(pack_Wy2, dim3(128), dim3(256), 0, stream, (const float*)d_in[4]);
  hipLaunchKernelGGL(pack_Wy3, dim3(64), dim3(256), 0, stream, (const float*)d_in[6]);
  hipLaunchKernelGGL(pack_We1s, dim3(128), dim3(256), 0, stream, (const float*)d_in[8]);
  hipLaunchKernelGGL(pack_WRU, dim3(1024), dim3(256), 0, stream,
                     (const float*)d_in[12], (const float*)d_in[13],
                     (const float*)d_in[15], (const float*)d_in[16]);
  hipLaunchKernelGGL(pack_WP, dim3(384), dim3(256), 0, stream,
                     (const float*)d_in[18]);
  hipLaunchKernelGGL(pack_Whh, dim3(128), dim3(256), 0, stream,
                     (const float*)d_in[19]);
  hipLaunchKernelGGL(conv_h, dim3((B_ * T_ * H_) / 256), dim3(256), 0, stream, h);
  hipLaunchKernelGGL(init_kernel, dim3(256), dim3(256), 0, stream,
                     (const float*)d_in[1]);
  hipLaunchKernelGGL(hproj_kernel, dim3(8, 512), dim3(256), 0, stream, h,
                     (const float*)d_in[8]);

  hipLaunchKernelGGL(k_loop, dim3(256), dim3(512), 0, stream, out);
}

// Round 10
// 12472.764 us; speedup vs baseline: 11.4936x; 11.4936x over previous
//
#include <hip/hip_runtime.h>

#define B_ 128
#define T_ 256
#define H_ 512
#define O_ 256
#define X_ 768

typedef unsigned short u16;
typedef unsigned int u32;

#if __has_builtin(__builtin_amdgcn_exp2f)
#define EXP2(x) __builtin_amdgcn_exp2f(x)
#else
#define EXP2(x) exp2f(x)
#endif
#if __has_builtin(__builtin_amdgcn_rcpf)
#define RCPF(x) __builtin_amdgcn_rcpf(x)
#else
#define RCPF(x) (1.0f / (x))
#endif

#define LOG2E_F 1.4426950408889634f
#define TWOLOG2E_F 2.8853900817779268f

typedef __attribute__((ext_vector_type(8))) short short8;
typedef __attribute__((ext_vector_type(4))) float f32x4;
typedef __attribute__((ext_vector_type(4))) unsigned int u32x4;

__device__ __forceinline__ float bf2f(u16 v) {
  union { u32 u; float f; } c; c.u = ((u32)v) << 16; return c.f;
}
__device__ __forceinline__ u16 f2bf(float f) {
  union { float f; u32 u; } c; c.f = f;
  return (u16)((c.u + 0x7FFFu + ((c.u >> 16) & 1u)) >> 16);
}
__device__ __forceinline__ float ftanh(float x) {
  x = fminf(fmaxf(x, -40.f), 40.f);
  float z = EXP2(x * TWOLOG2E_F);
  return (z - 1.0f) * RCPF(z + 1.0f);
}
__device__ __forceinline__ float fsigm(float x) {
  x = fminf(fmaxf(x, -40.f), 40.f);
  return RCPF(1.0f + EXP2(-x * LOG2E_F));
}

// ---- module-scope scratch ----
__device__ u16 g_hp[(size_t)B_ * T_ * H_];   // bf16 h_proj
__device__ u16 g_hb[(size_t)B_ * T_ * H_];   // bf16 copy of h
__device__ float g_s[B_ * H_];               // fp32 state
__device__ float g_u[B_ * H_];
__device__ float g_sp[B_ * H_];              // s @ We1_s + be1
__device__ float g_p[B_ * H_];               // [y2,y2,c] @ WP (+bh fold)

// composite-weight scratch (fp32, one-time)
__device__ float g_wcru[512 * 1024];         // Wy3 @ [Wxr_top | Wxu_top]
__device__ float g_wch[512 * 512];           // Wy3 @ Wxh_top
__device__ float g_bru[1024];                // br|bu + by3 @ Wx_top
__device__ float g_bh[512];                  // by3 @ Wxh_top

// Fragment-packed activation A buffer (bf16 hi + lo residual), NKT=96 k-tiles.
// col slabs: [0,512)=y2, [512,1024)=y2 dup, [1024,1536)=c, [1536,2048)=s,
//            [2048,2560)=r*s, [2560,3072)=y1
// idx = ((rt*96 + kt)*512) + ((kg*16 + r)*8) + j ; rt=b>>4, r=b&15,
// kt=col>>5, kg=(col>>3)&3, j=col&7
__device__ u16 g_ah[(size_t)8 * 96 * 512];
__device__ u16 g_al[(size_t)8 * 96 * 512];

// Fragment-packed bf16 weights: idx = ((ntile*NKT + kt)*512 + l*8 + j)
__device__ u16 Wy1p[(size_t)32 * 16 * 512];
__device__ u16 Wy2p[(size_t)32 * 16 * 512];
__device__ u16 Wy3p[(size_t)16 * 16 * 512];
__device__ u16 We1sp[(size_t)32 * 16 * 512];
// WRUp: N=1024 (r|u), K=2048: kt0-15=Wc_hi, 16-31=Wc_lo, 32-47=Wx_mid, 48-63=Wh
__device__ u16 WRUp[(size_t)64 * 64 * 512];
// WPp: N=512, K=1536: kt0-15=Wch_hi, 16-31=Wch_lo, 32-47=Wxh_mid
__device__ u16 WPp[(size_t)32 * 48 * 512];
// Whhp: N=512, K=512
__device__ u16 Whhp[(size_t)32 * 16 * 512];

__device__ u16 cby1[H_];
__device__ u16 cby2[H_];
__device__ u16 cby3[O_];
__device__ u16 cbe1[H_];
__device__ u16 cWe2[H_];

__device__ __forceinline__ void store_packed(int b, int col, float v) {
  u16 hi = f2bf(v);
  size_t idx = (((size_t)(b >> 4) * 96 + (col >> 5)) << 9) +
               ((((col >> 3) & 3) * 16 + (b & 15)) << 3) + (col & 7);
  g_ah[idx] = hi;
  g_al[idx] = f2bf(v - bf2f(hi));
}

#define DEF_CONV(NAME, ARR, N)                                     \
  __global__ void conv_##NAME(const float* __restrict__ s) {       \
    int i = blockIdx.x * 256 + threadIdx.x;                        \
    if (i < (N)) ARR[i] = f2bf(s[i]);                              \
  }

DEF_CONV(by1, cby1, H_)
DEF_CONV(by2, cby2, H_)
DEF_CONV(by3, cby3, O_)
DEF_CONV(be1, cbe1, H_)
DEF_CONV(We2, cWe2, H_)

__global__ void conv_h(const float* __restrict__ s) {
  size_t i = (size_t)blockIdx.x * 256 + threadIdx.x;
  g_hb[i] = f2bf(s[i]);
}

// ---- composite GEMM: C[MODE] = A(512x256,lda256) @ B(256x512,ldb512) ----
// MODE selects the __device__ destination INSIDE device code (host code must
// never take the address of a __device__ symbol — that was the r4-r7 abort).
template <int MODE>
__global__ void __launch_bounds__(256) fgemm_comp(const float* __restrict__ A,
                                                  const float* __restrict__ B) {
  float* C = (MODE == 0) ? g_wcru : (MODE == 1) ? (g_wcru + 512) : g_wch;
  const int ldc = (MODE == 2) ? 512 : 1024;
  __shared__ float Ast[32][72];
  __shared__ float Bs[32][72];
  const int tid = threadIdx.x;
  const int tx = tid & 15, ty = tid >> 4;
  const int n0 = blockIdx.x << 6;
  const int m0 = blockIdx.y << 6;
  float acc[4][4] = {};
  for (int k0 = 0; k0 < 256; k0 += 32) {
    {
      int row = tid >> 2, kq = (tid & 3) << 3;
      const float* src = A + (size_t)(m0 + row) * 256 + k0 + kq;
      float4 v0 = *(const float4*)src;
      float4 v1 = *(const float4*)(src + 4);
      Ast[kq + 0][row] = v0.x; Ast[kq + 1][row] = v0.y;
      Ast[kq + 2][row] = v0.z; Ast[kq + 3][row] = v0.w;
      Ast[kq + 4][row] = v1.x; Ast[kq + 5][row] = v1.y;
      Ast[kq + 6][row] = v1.z; Ast[kq + 7][row] = v1.w;
    }
    {
      int kr = tid >> 3, nq = (tid & 7) << 3;
      const float* src = B + (size_t)(k0 + kr) * 512 + n0 + nq;
      float4 v0 = *(const float4*)src;
      float4 v1 = *(const float4*)(src + 4);
      float* d = &Bs[kr][nq];
      d[0] = v0.x; d[1] = v0.y; d[2] = v0.z; d[3] = v0.w;
      d[4] = v1.x; d[5] = v1.y; d[6] = v1.z; d[7] = v1.w;
    }
    __syncthreads();
#pragma unroll
    for (int kk = 0; kk < 32; ++kk) {
      const float4 a4 = *(const float4*)&Ast[kk][ty << 2];
      const float4 b4 = *(const float4*)&Bs[kk][tx << 2];
      float av[4] = {a4.x, a4.y, a4.z, a4.w};
      float bv[4] = {b4.x, b4.y, b4.z, b4.w};
#pragma unroll
      for (int i = 0; i < 4; ++i)
#pragma unroll
        for (int j = 0; j < 4; ++j) acc[i][j] = fmaf(av[i], bv[j], acc[i][j]);
    }
    __syncthreads();
  }
#pragma unroll
  for (int i = 0; i < 4; ++i)
#pragma unroll
    for (int j = 0; j < 4; ++j)
      C[(size_t)(m0 + ty * 4 + i) * ldc + n0 + tx * 4 + j] = acc[i][j];
}

__global__ void bias_fold(const float* __restrict__ by3,
                          const float* __restrict__ Wxr,
                          const float* __restrict__ Wxu,
                          const float* __restrict__ br,
                          const float* __restrict__ bu,
                          const float* __restrict__ Wxh) {
  int n = blockIdx.x * 256 + threadIdx.x;
  if (n < 1024) {
    const float* W = (n < 512) ? Wxr : Wxu;
    int nn = n & 511;
    float acc = (n < 512) ? br[nn] : bu[nn];
    for (int k = 0; k < 256; ++k) acc += by3[k] * W[(size_t)k * 512 + nn];
    g_bru[n] = acc;
  } else if (n < 1536) {
    int nn = n - 1024;
    float acc = 0.f;
    for (int k = 0; k < 256; ++k) acc += by3[k] * Wxh[(size_t)k * 512 + nn];
    g_bh[nn] = acc;
  }
}

// ---- weight packers ----
#define DEF_PACKB(NAME, DST, NKT, SRCEXPR)                               \
  __global__ void NAME(const float* __restrict__ S0) {                   \
    int gid = blockIdx.x * 256 + threadIdx.x;                            \
    int l = gid & 63, kt = (gid >> 6) % (NKT);                           \
    int ntile = gid / (64 * (NKT));                                      \
    int n = ntile * 16 + (l & 15);                                       \
    __align__(16) u16 tmp[8];                                            \
    _Pragma("unroll")                                                    \
    for (int j = 0; j < 8; ++j) {                                        \
      int k = kt * 32 + ((l >> 4) << 3) + j;                             \
      tmp[j] = f2bf(SRCEXPR);                                            \
    }                                                                    \
    *(uint4*)(DST + (size_t)gid * 8) = *(const uint4*)tmp;               \
  }

DEF_PACKB(pack_Wy1, Wy1p, 16, S0[(size_t)k * 512 + n])
DEF_PACKB(pack_Wy2, Wy2p, 16, S0[(size_t)k * 512 + n])
DEF_PACKB(pack_Wy3, Wy3p, 16, S0[(size_t)k * 256 + n])
DEF_PACKB(pack_We1s, We1sp, 16, S0[(size_t)(512 + k) * 512 + n])

__global__ void pack_WRU(const float* __restrict__ Wxr, const float* __restrict__ Whr,
                         const float* __restrict__ Wxu, const float* __restrict__ Whu) {
  int gid = blockIdx.x * 256 + threadIdx.x;   // 64 ntile * 64 kt * 64 lanes
  int l = gid & 63, kt = (gid >> 6) & 63;
  int ntile = gid >> 12;
  int n = ntile * 16 + (l & 15);
  int nn = n & 511;
  __align__(16) u16 tmp[8];
#pragma unroll
  for (int j = 0; j < 8; ++j) {
    int k = kt * 32 + ((l >> 4) << 3) + j;   // 0..2047
    float v;
    if (k < 512) v = g_wcru[(size_t)k * 1024 + n];
    else if (k < 1024) {
      float x = g_wcru[(size_t)(k - 512) * 1024 + n];
      v = x - bf2f(f2bf(x));
    } else if (k < 1536) {
      v = (n < 512) ? Wxr[(size_t)(k - 1024 + 256) * 512 + nn]
                    : Wxu[(size_t)(k - 1024 + 256) * 512 + nn];
    } else {
      v = (n < 512) ? Whr[(size_t)(k - 1536) * 512 + nn]
                    : Whu[(size_t)(k - 1536) * 512 + nn];
    }
    tmp[j] = f2bf(v);
  }
  *(uint4*)(WRUp + (size_t)gid * 8) = *(const uint4*)tmp;
}

__global__ void pack_WP(const float* __restrict__ Wxh) {
  int gid = blockIdx.x * 256 + threadIdx.x;   // 32 ntile * 48 kt * 64 lanes
  int l = gid & 63, kt = (gid >> 6) % 48;
  int ntile = gid / (64 * 48);
  int n = ntile * 16 + (l & 15);
  __align__(16) u16 tmp[8];
#pragma unroll
  for (int j = 0; j < 8; ++j) {
    int k = kt * 32 + ((l >> 4) << 3) + j;   // 0..1535
    float v;
    if (k < 512) v = g_wch[(size_t)k * 512 + n];
    else if (k < 1024) {
      float x = g_wch[(size_t)(k - 512) * 512 + n];
      v = x - bf2f(f2bf(x));
    } else {
      v = Wxh[(size_t)(k - 1024 + 256) * 512 + n];
    }
    tmp[j] = f2bf(v);
  }
  *(uint4*)(WPp + (size_t)gid * 8) = *(const uint4*)tmp;
}

__global__ void pack_Whh(const float* __restrict__ Whh) {
  int gid = blockIdx.x * 256 + threadIdx.x;   // 32 ntile * 16 kt * 64 lanes
  int l = gid & 63, kt = (gid >> 6) & 15;
  int ntile = gid >> 10;
  int n = ntile * 16 + (l & 15);
  __align__(16) u16 tmp[8];
#pragma unroll
  for (int j = 0; j < 8; ++j) {
    int k = kt * 32 + ((l >> 4) << 3) + j;
    tmp[j] = f2bf(Whh[(size_t)k * 512 + n]);
  }
  *(uint4*)(Whhp + (size_t)gid * 8) = *(const uint4*)tmp;
}

__global__ void init_kernel(const float* __restrict__ s0) {
  int g = blockIdx.x * blockDim.x + threadIdx.x;
  if (g < B_ * H_) {
    float v = s0[g];
    g_s[g] = v;
    int b = g >> 9, n = g & 511;
    store_packed(b, 1536 + n, v);
  }
}

// ---- h_proj = h @ We1[:H]  (fp32 in, bf16 out) ----
__global__ void __launch_bounds__(256) hproj_kernel(const float* __restrict__ hh,
                                                    const float* __restrict__ We1) {
  __shared__ float Ast[32][72];
  __shared__ float Bs[32][72];
  const int tid = threadIdx.x;
  const int tx = tid & 15, ty = tid >> 4;
  const int n0 = blockIdx.x << 6;
  const int m0 = blockIdx.y << 6;
  float acc[4][4] = {};
  for (int k0 = 0; k0 < H_; k0 += 32) {
    {
      int row = tid >> 2, kq = (tid & 3) << 3;
      const float* src = hh + (size_t)(m0 + row) * H_ + k0 + kq;
      float4 v0 = *(const float4*)src;
      float4 v1 = *(const float4*)(src + 4);
      Ast[kq + 0][row] = v0.x; Ast[kq + 1][row] = v0.y;
      Ast[kq + 2][row] = v0.z; Ast[kq + 3][row] = v0.w;
      Ast[kq + 4][row] = v1.x; Ast[kq + 5][row] = v1.y;
      Ast[kq + 6][row] = v1.z; Ast[kq + 7][row] = v1.w;
    }
    {
      int kr = tid >> 3, nq = (tid & 7) << 3;
      const float* src = We1 + (size_t)(k0 + kr) * H_ + n0 + nq;
      float4 v0 = *(const float4*)src;
      float4 v1 = *(const float4*)(src + 4);
      float* d = &Bs[kr][nq];
      d[0] = v0.x; d[1] = v0.y; d[2] = v0.z; d[3] = v0.w;
      d[4] = v1.x; d[5] = v1.y; d[6] = v1.z; d[7] = v1.w;
    }
    __syncthreads();
#pragma unroll
    for (int kk = 0; kk < 32; ++kk) {
      const float4 a4 = *(const float4*)&Ast[kk][ty << 2];
      const float4 b4 = *(const float4*)&Bs[kk][tx << 2];
      float av[4] = {a4.x, a4.y, a4.z, a4.w};
      float bv[4] = {b4.x, b4.y, b4.z, b4.w};
#pragma unroll
      for (int i = 0; i < 4; ++i)
#pragma unroll
        for (int j = 0; j < 4; ++j) acc[i][j] = fmaf(av[i], bv[j], acc[i][j]);
    }
    __syncthreads();
  }
#pragma unroll
  for (int i = 0; i < 4; ++i) {
    u16* dst = g_hp + (size_t)(m0 + ty * 4 + i) * H_ + n0 + tx * 4;
    u32 w0 = (u32)f2bf(acc[i][0]) | ((u32)f2bf(acc[i][1]) << 16);
    u32 w1 = (u32)f2bf(acc[i][2]) | ((u32)f2bf(acc[i][3]) << 16);
    *(u32*)dst = w0;
    *(u32*)(dst + 2) = w1;
  }
}

#define FMA8(pk, sk, A)                                          \
  {                                                              \
    u32 ww0 = pk.x, ww1 = pk.y, ww2 = pk.z, ww3 = pk.w;          \
    A[0] = fmaf(sk, bf2f((u16)(ww0 & 0xffffu)), A[0]);           \
    A[1] = fmaf(sk, bf2f((u16)(ww0 >> 16)), A[1]);               \
    A[2] = fmaf(sk, bf2f((u16)(ww1 & 0xffffu)), A[2]);           \
    A[3] = fmaf(sk, bf2f((u16)(ww1 >> 16)), A[3]);               \
    A[4] = fmaf(sk, bf2f((u16)(ww2 & 0xffffu)), A[4]);           \
    A[5] = fmaf(sk, bf2f((u16)(ww2 >> 16)), A[5]);               \
    A[6] = fmaf(sk, bf2f((u16)(ww3 & 0xffffu)), A[6]);           \
    A[7] = fmaf(sk, bf2f((u16)(ww3 >> 16)), A[7]);               \
  }

// ---- GEMM core (M=16, N=64): 8-wave k-split, hi/lo A ----
template <int KTA0, int NKT_B, int KTW>
__device__ __forceinline__ void gemm_core(const u16* __restrict__ BP, int mt,
                                          int nb, int tid, float* smem) {
  const int l = tid & 63, w = tid >> 6;
  f32x4 acc0 = {0.f, 0.f, 0.f, 0.f}, acc1 = {0.f, 0.f, 0.f, 0.f};
  f32x4 acc2 = {0.f, 0.f, 0.f, 0.f}, acc3 = {0.f, 0.f, 0.f, 0.f};
  const size_t abase = (((size_t)mt * 96 + KTA0 + w * KTW) << 9) + l * 8;
#pragma unroll
  for (int kk = 0; kk < KTW; ++kk) {
    short8 ah = *(const short8*)(g_ah + abase + (size_t)kk * 512);
    short8 al = *(const short8*)(g_al + abase + (size_t)kk * 512);
    const size_t bbase =
        (((size_t)(nb * 4) * NKT_B + w * KTW + kk) << 9) + l * 8;
    short8 b0 = *(const short8*)(BP + bbase);
    short8 b1 = *(const short8*)(BP + bbase + ((size_t)NKT_B << 9));
    short8 b2 = *(const short8*)(BP + bbase + ((size_t)2 * NKT_B << 9));
    short8 b3 = *(const short8*)(BP + bbase + ((size_t)3 * NKT_B << 9));
    acc0 = __builtin_amdgcn_mfma_f32_16x16x32_bf16(ah, b0, acc0, 0, 0, 0);
    acc0 = __builtin_amdgcn_mfma_f32_16x16x32_bf16(al, b0, acc0, 0, 0, 0);
    acc1 = __builtin_amdgcn_mfma_f32_16x16x32_bf16(ah, b1, acc1, 0, 0, 0);
    acc1 = __builtin_amdgcn_mfma_f32_16x16x32_bf16(al, b1, acc1, 0, 0, 0);
    acc2 = __builtin_amdgcn_mfma_f32_16x16x32_bf16(ah, b2, acc2, 0, 0, 0);
    acc2 = __builtin_amdgcn_mfma_f32_16x16x32_bf16(al, b2, acc2, 0, 0, 0);
    acc3 = __builtin_amdgcn_mfma_f32_16x16x32_bf16(ah, b3, acc3, 0, 0, 0);
    acc3 = __builtin_amdgcn_mfma_f32_16x16x32_bf16(al, b3, acc3, 0, 0, 0);
  }
  float* pw = smem + w * 1024;
  const int r0 = (l >> 4) * 4, c0 = l & 15;
#pragma unroll
  for (int r = 0; r < 4; ++r) {
    pw[(r0 + r) * 64 + 0 + c0] = acc0[r];
    pw[(r0 + r) * 64 + 16 + c0] = acc1[r];
    pw[(r0 + r) * 64 + 32 + c0] = acc2[r];
    pw[(r0 + r) * 64 + 48 + c0] = acc3[r];
  }
  __syncthreads();
}

// ---- GEMM core (M=32, N=32): halves B-slab traffic vs M=16/N=64 ----
template <int KTA0, int NKT_B, int KTW>
__device__ __forceinline__ void gemm_core32(const u16* __restrict__ BP, int mt2,
                                            int nb2, int tid, float* smem) {
  const int l = tid & 63, w = tid >> 6;
  f32x4 a00 = {0.f, 0.f, 0.f, 0.f}, a01 = {0.f, 0.f, 0.f, 0.f};
  f32x4 a10 = {0.f, 0.f, 0.f, 0.f}, a11 = {0.f, 0.f, 0.f, 0.f};
  const size_t ab0 = (((size_t)(mt2 * 2) * 96 + KTA0 + w * KTW) << 9) + l * 8;
  const size_t ab1 = (((size_t)(mt2 * 2 + 1) * 96 + KTA0 + w * KTW) << 9) + l * 8;
#pragma unroll
  for (int kk = 0; kk < KTW; ++kk) {
    short8 ah0 = *(const short8*)(g_ah + ab0 + (size_t)kk * 512);
    short8 al0 = *(const short8*)(g_al + ab0 + (size_t)kk * 512);
    short8 ah1 = *(const short8*)(g_ah + ab1 + (size_t)kk * 512);
    short8 al1 = *(const short8*)(g_al + ab1 + (size_t)kk * 512);
    const size_t bb0 =
        (((size_t)(nb2 * 2) * NKT_B + w * KTW + kk) << 9) + l * 8;
    short8 b0 = *(const short8*)(BP + bb0);
    short8 b1 = *(const short8*)(BP + bb0 + ((size_t)NKT_B << 9));
    a00 = __builtin_amdgcn_mfma_f32_16x16x32_bf16(ah0, b0, a00, 0, 0, 0);
    a00 = __builtin_amdgcn_mfma_f32_16x16x32_bf16(al0, b0, a00, 0, 0, 0);
    a01 = __builtin_amdgcn_mfma_f32_16x16x32_bf16(ah0, b1, a01, 0, 0, 0);
    a01 = __builtin_amdgcn_mfma_f32_16x16x32_bf16(al0, b1, a01, 0, 0, 0);
    a10 = __builtin_amdgcn_mfma_f32_16x16x32_bf16(ah1, b0, a10, 0, 0, 0);
    a10 = __builtin_amdgcn_mfma_f32_16x16x32_bf16(al1, b0, a10, 0, 0, 0);
    a11 = __builtin_amdgcn_mfma_f32_16x16x32_bf16(ah1, b1, a11, 0, 0, 0);
    a11 = __builtin_amdgcn_mfma_f32_16x16x32_bf16(al1, b1, a11, 0, 0, 0);
  }
  float* pw = smem + w * 1024;
  const int r0 = (l >> 4) * 4, c0 = l & 15;
#pragma unroll
  for (int r = 0; r < 4; ++r) {
    pw[(r0 + r) * 32 + c0] = a00[r];
    pw[(r0 + r) * 32 + 16 + c0] = a01[r];
    pw[(16 + r0 + r) * 32 + c0] = a10[r];
    pw[(16 + r0 + r) * 32 + 16 + c0] = a11[r];
  }
  __syncthreads();
}

#define EPI_V(row, col, LD)                                          \
  float v = 0.f;                                                     \
  _Pragma("unroll") for (int ww = 0; ww < 8; ++ww)                   \
      v += smem[ww * 1024 + (row) * (LD) + (col)];

// ---- k1: y1 (0-63, 32x32 tiles) || sp (64-127) ----
__global__ void __launch_bounds__(512) k1_y1sp() {
  __shared__ __align__(16) float smem[8192];
  const int tid = threadIdx.x;
  const int bid = blockIdx.x;
  if (bid < 64) {
    const int mt2 = bid >> 4, nb2 = bid & 15;
    gemm_core32<48, 16, 2>(Wy1p, mt2, nb2, tid, smem);
#pragma unroll
    for (int rep = 0; rep < 2; ++rep) {
      int idx = rep * 512 + tid, row = idx >> 5, col = idx & 31;
      EPI_V(row, col, 32);
      int gb = mt2 * 32 + row, gc = nb2 * 32 + col;
      v += bf2f(cby1[gc]);
      store_packed(gb, 2560 + gc, ftanh(v));
    }
  } else {
    const int blk2 = bid - 64;
    const int mt2 = blk2 >> 4, nb2 = blk2 & 15;
    gemm_core32<48, 16, 2>(We1sp, mt2, nb2, tid, smem);
#pragma unroll
    for (int rep = 0; rep < 2; ++rep) {
      int idx = rep * 512 + tid, row = idx >> 5, col = idx & 31;
      EPI_V(row, col, 32);
      int gb = mt2 * 32 + row, gc = nb2 * 32 + col;
      g_sp[gb * H_ + gc] = v + bf2f(cbe1[gc]);
    }
  }
}

// ---- k2: y2 (0-63, 32x32 tiles) || attn (64-191) ----
__global__ void __launch_bounds__(512) k2_y2attn() {
  __shared__ __align__(16) float smem[8192];
  __shared__ float red[16];
  const int tid = threadIdx.x;
  const int bid = blockIdx.x;
  if (bid < 64) {
    const int mt2 = bid >> 4, nb2 = bid & 15;
    gemm_core32<80, 16, 2>(Wy2p, mt2, nb2, tid, smem);
#pragma unroll
    for (int rep = 0; rep < 2; ++rep) {
      int idx = rep * 512 + tid, row = idx >> 5, col = idx & 31;
      EPI_V(row, col, 32);
      int gb = mt2 * 32 + row, gc = nb2 * 32 + col;
      v += bf2f(cby2[gc]);
      float y2v = ftanh(v);
      store_packed(gb, gc, y2v);
      store_packed(gb, 512 + gc, y2v);
    }
  } else {
    const int b = bid - 64;
    float* sm_e = smem + 1024;
    {
      float spv = g_sp[b * H_ + tid];
      float w2 = bf2f(cWe2[tid]);
      smem[2 * tid] = spv * TWOLOG2E_F;
      smem[2 * tid + 1] = -2.0f * w2;
    }
    __syncthreads();
    const int wv = tid >> 6, l = tid & 63;
    const int rr = l & 15, q = l >> 4;
#pragma unroll
    for (int p = 0; p < 2; ++p) {
      int tp = p * 128 + wv * 16 + rr;
      const u16* rowp = g_hp + ((size_t)(b * T_ + tp) << 9);
      float part = 0.f;
      for (int i = 0; i < 16; ++i) {
        int c0 = i * 32 + q * 8;
        u32x4 pk = __builtin_nontemporal_load((const u32x4*)(rowp + c0));
        const float4* swp = reinterpret_cast<const float4*>(smem + 2 * c0);
        float4 f0 = swp[0], f1 = swp[1], f2 = swp[2], f3 = swp[3];
        u32 ww[4] = {pk.x, pk.y, pk.z, pk.w};
        {
          float h0 = bf2f((u16)(ww[0] & 0xffffu)), h1 = bf2f((u16)(ww[0] >> 16));
          float x0 = fmaf(h0, TWOLOG2E_F, f0.x);
          float x1 = fmaf(h1, TWOLOG2E_F, f0.z);
          part = fmaf(f0.y, RCPF(EXP2(x0) + 1.f), part);
          part = fmaf(f0.w, RCPF(EXP2(x1) + 1.f), part);
        }
        {
          float h0 = bf2f((u16)(ww[1] & 0xffffu)), h1 = bf2f((u16)(ww[1] >> 16));
          float x0 = fmaf(h0, TWOLOG2E_F, f1.x);
          float x1 = fmaf(h1, TWOLOG2E_F, f1.z);
          part = fmaf(f1.y, RCPF(EXP2(x0) + 1.f), part);
          part = fmaf(f1.w, RCPF(EXP2(x1) + 1.f), part);
        }
        {
          float h0 = bf2f((u16)(ww[2] & 0xffffu)), h1 = bf2f((u16)(ww[2] >> 16));
          float x0 = fmaf(h0, TWOLOG2E_F, f2.x);
          float x1 = fmaf(h1, TWOLOG2E_F, f2.z);
          part = fmaf(f2.y, RCPF(EXP2(x0) + 1.f), part);
          part = fmaf(f2.w, RCPF(EXP2(x1) + 1.f), part);
        }
        {
          float h0 = bf2f((u16)(ww[3] & 0xffffu)), h1 = bf2f((u16)(ww[3] >> 16));
          float x0 = fmaf(h0, TWOLOG2E_F, f3.x);
          float x1 = fmaf(h1, TWOLOG2E_F, f3.z);
          part = fmaf(f3.y, RCPF(EXP2(x0) + 1.f), part);
          part = fmaf(f3.w, RCPF(EXP2(x1) + 1.f), part);
        }
      }
      part += __shfl_xor(part, 16, 64);
      part += __shfl_xor(part, 32, 64);
      if (q == 0) sm_e[tp] = part;
    }
    __syncthreads();
    float v = (tid < T_) ? sm_e[tid] : -3.0e38f;
    float m = v;
#pragma unroll
    for (int off = 32; off > 0; off >>= 1) m = fmaxf(m, __shfl_xor(m, off, 64));
    if (l == 0) red[wv] = m;
    __syncthreads();
    m = fmaxf(fmaxf(fmaxf(red[0], red[1]), fmaxf(red[2], red[3])),
              fmaxf(fmaxf(red[4], red[5]), fmaxf(red[6], red[7])));
    float pe = (tid < T_) ? EXP2((v - m) * LOG2E_F) : 0.f;
    float ssum = pe;
#pragma unroll
    for (int off = 32; off > 0; off >>= 1) ssum += __shfl_xor(ssum, off, 64);
    if (l == 0) red[8 + wv] = ssum;
    __syncthreads();
    float tot = (red[8] + red[9]) + (red[10] + red[11]) +
                (red[12] + red[13]) + (red[14] + red[15]);
    float ainv = RCPF(tot);
    if (tid < T_) sm_e[tid] = pe * ainv;
    __syncthreads();
    { // c = a @ h -> slab c (col 1024+)
      const int ts = tid >> 6, c = tid & 63, n0 = c << 3;
      float a[8] = {};
      for (int tp = ts * 32; tp < ts * 32 + 32; ++tp) {
        u32x4 pk = __builtin_nontemporal_load(
            (const u32x4*)(g_hb + ((size_t)(b * T_ + tp) << 9) + n0));
        float av = sm_e[tp];
        FMA8(pk, av, a);
      }
      float* pt = smem + 1536 + ts * 512 + n0;
#pragma unroll
      for (int j = 0; j < 8; ++j) pt[j] = a[j];
    }
    __syncthreads();
    {
      float v2 = 0.f;
#pragma unroll
      for (int kk = 0; kk < 8; ++kk) v2 += smem[1536 + kk * 512 + tid];
      store_packed(b, 1024 + tid, v2);
    }
  }
}

// ---- k3: y3out (0-31) || RU (32-159, 32x32) || P (160-223, 32x32) ----
__global__ void __launch_bounds__(512) k3_y3rup(float* __restrict__ out, int t) {
  __shared__ __align__(16) float smem[8192];
  const int tid = threadIdx.x;
  const int bid = blockIdx.x;
  if (bid < 32) {
    const int mt3 = bid >> 2, nb3 = bid & 3;
    gemm_core<0, 16, 2>(Wy3p, mt3, nb3, tid, smem);
#pragma unroll
    for (int rep = 0; rep < 2; ++rep) {
      int idx = rep * 512 + tid, row = idx >> 6, col = idx & 63;
      EPI_V(row, col, 64);
      int gb = mt3 * 16 + row, gc = nb3 * 64 + col;
      v += bf2f(cby3[gc]);
      out[((size_t)gb * T_ + t) * O_ + gc] = v;
    }
  } else if (bid < 160) {
    const int idx2 = bid - 32;
    const int mt2 = idx2 >> 5, nb2 = idx2 & 31;
    gemm_core32<0, 64, 8>(WRUp, mt2, nb2, tid, smem);
#pragma unroll
    for (int rep = 0; rep < 2; ++rep) {
      int idx = rep * 512 + tid, row = idx >> 5, col = idx & 31;
      EPI_V(row, col, 32);
      int gb = mt2 * 32 + row, gc = nb2 * 32 + col;
      v += g_bru[gc];
      if (gc < 512) {
        float rv = fsigm(v);
        float rs = rv * g_s[gb * H_ + gc];
        store_packed(gb, 2048 + gc, rs);
      } else {
        g_u[gb * H_ + (gc - 512)] = fsigm(v);
      }
    }
  } else {
    const int idx2 = bid - 160;
    const int mt2 = idx2 >> 4, nb2 = idx2 & 15;
    gemm_core32<0, 48, 6>(WPp, mt2, nb2, tid, smem);
#pragma unroll
    for (int rep = 0; rep < 2; ++rep) {
      int idx = rep * 512 + tid, row = idx >> 5, col = idx & 31;
      EPI_V(row, col, 32);
      int gb = mt2 * 32 + row, gc = nb2 * 32 + col;
      g_p[gb * H_ + gc] = v + g_bh[gc];
    }
  }
}

// ---- k4: HC + s-update (64 blocks, 16x64) ----
__global__ void __launch_bounds__(512) k4_hc() {
  __shared__ __align__(16) float smem[8192];
  const int tid = threadIdx.x;
  const int bid = blockIdx.x;
  const int mt = bid >> 3, nb = bid & 7;
  gemm_core<64, 16, 2>(Whhp, mt, nb, tid, smem);
#pragma unroll
  for (int rep = 0; rep < 2; ++rep) {
    int idx = rep * 512 + tid, row = idx >> 6, col = idx & 63;
    EPI_V(row, col, 64);
    int gb = mt * 16 + row, gc = nb * 64 + col;
    int sidx = gb * H_ + gc;
    v += g_p[sidx];
    float hc = ftanh(v);
    float uu = g_u[sidx];
    float sn = (1.f - uu) * hc + uu * g_s[sidx];
    g_s[sidx] = sn;
    store_packed(gb, 1536 + gc, sn);
  }
}

extern "C" void kernel_launch(void* const* d_in, const int* in_sizes, int n_in,
                              void* d_out, int out_size, void* d_ws, size_t ws_size,
                              hipStream_t stream) {
  (void)in_sizes; (void)n_in; (void)out_size; (void)d_ws; (void)ws_size;
  const float* h = (const float*)d_in[0];
  float* out = (float*)d_out;

#define CONV(NAME, IDX, N) \
  hipLaunchKernelGGL(conv_##NAME, dim3(((N) + 255) / 256), dim3(256), 0, stream, \
                     (const float*)d_in[IDX])
  CONV(by1, 3, H_);
  CONV(by2, 5, H_);
  CONV(by3, 7, O_);
  CONV(be1, 9, H_);
  CONV(We2, 10, H_);
  // d_in[11] = be2: softmax shift-invariant, unused
#undef CONV
  // composite weights: destinations selected in device code (never pass
  // __device__ symbols as host-side kernel args — r4-r7 abort cause)
  hipLaunchKernelGGL((fgemm_comp<0>), dim3(8, 8), dim3(256), 0, stream,
                     (const float*)d_in[6], (const float*)d_in[12]);
  hipLaunchKernelGGL((fgemm_comp<1>), dim3(8, 8), dim3(256), 0, stream,
                     (const float*)d_in[6], (const float*)d_in[15]);
  hipLaunchKernelGGL((fgemm_comp<2>), dim3(8, 8), dim3(256), 0, stream,
                     (const float*)d_in[6], (const float*)d_in[18]);
  hipLaunchKernelGGL(bias_fold, dim3(6), dim3(256), 0, stream,
                     (const float*)d_in[7], (const float*)d_in[12],
                     (const float*)d_in[15], (const float*)d_in[14],
                     (const float*)d_in[17], (const float*)d_in[18]);
  hipLaunchKernelGGL(pack_Wy1, dim3(128), dim3(256), 0, stream, (const float*)d_in[2]);
  hipLaunchKernelGGL(pack_Wy2, dim3(128), dim3(256), 0, stream, (const float*)d_in[4]);
  hipLaunchKernelGGL(pack_Wy3, dim3(64), dim3(256), 0, stream, (const float*)d_in[6]);
  hipLaunchKernelGGL(pack_We1s, dim3(128), dim3(256), 0, stream, (const float*)d_in[8]);
  hipLaunchKernelGGL(pack_WRU, dim3(1024), dim3(256), 0, stream,
                     (const float*)d_in[12], (const float*)d_in[13],
                     (const float*)d_in[15], (const float*)d_in[16]);
  hipLaunchKernelGGL(pack_WP, dim3(384), dim3(256), 0, stream,
                     (const float*)d_in[18]);
  hipLaunchKernelGGL(pack_Whh, dim3(128), dim3(256), 0, stream,
                     (const float*)d_in[19]);
  hipLaunchKernelGGL(conv_h, dim3((B_ * T_ * H_) / 256), dim3(256), 0, stream, h);
  hipLaunchKernelGGL(init_kernel, dim3(256), dim3(256), 0, stream,
                     (const float*)d_in[1]);
  hipLaunchKernelGGL(hproj_kernel, dim3(8, 512), dim3(256), 0, stream, h,
                     (const float*)d_in[8]);

  for (int t = 0; t < T_; ++t) {
    hipLaunchKernelGGL(k1_y1sp, dim3(128), dim3(512), 0, stream);
    hipLaunchKernelGGL(k2_y2attn, dim3(192), dim3(512), 0, stream);
    hipLaunchKernelGGL(k3_y3rup, dim3(224), dim3(512), 0, stream, out, t);
    hipLaunchKernelGGL(k4_hc, dim3(64), dim3(512), 0, stream);
  }
}

// Round 11
// 8648.200 us; speedup vs baseline: 16.5766x; 1.4422x over previous
//
#include <hip/hip_runtime.h>

#define B_ 128
#define T_ 256
#define H_ 512
#define O_ 256
#define X_ 768

typedef unsigned short u16;
typedef unsigned int u32;

#if __has_builtin(__builtin_amdgcn_exp2f)
#define EXP2(x) __builtin_amdgcn_exp2f(x)
#else
#define EXP2(x) exp2f(x)
#endif
#if __has_builtin(__builtin_amdgcn_rcpf)
#define RCPF(x) __builtin_amdgcn_rcpf(x)
#else
#define RCPF(x) (1.0f / (x))
#endif

#define LOG2E_F 1.4426950408889634f
#define TWOLOG2E_F 2.8853900817779268f

typedef __attribute__((ext_vector_type(8))) short short8;
typedef __attribute__((ext_vector_type(4))) float f32x4;

__device__ __forceinline__ float bf2f(u16 v) {
  union { u32 u; float f; } c; c.u = ((u32)v) << 16; return c.f;
}
__device__ __forceinline__ u16 f2bf(float f) {
  union { float f; u32 u; } c; c.f = f;
  return (u16)((c.u + 0x7FFFu + ((c.u >> 16) & 1u)) >> 16);
}
__device__ __forceinline__ float ftanh(float x) {
  x = fminf(fmaxf(x, -40.f), 40.f);
  float z = EXP2(x * TWOLOG2E_F);
  return (z - 1.0f) * RCPF(z + 1.0f);
}
__device__ __forceinline__ float fsigm(float x) {
  x = fminf(fmaxf(x, -40.f), 40.f);
  return RCPF(1.0f + EXP2(-x * LOG2E_F));
}

// ---- module-scope scratch ----
__device__ u16 g_hp[(size_t)B_ * T_ * H_];   // bf16 h_proj
__device__ u16 g_hb[(size_t)B_ * T_ * H_];   // bf16 copy of h
__device__ float g_s[B_ * H_];               // fp32 state
__device__ float g_u[B_ * H_];
__device__ float g_sp[B_ * H_];              // s @ We1_s + be1
__device__ float g_p[B_ * H_];               // [y2,y2,c] @ WP (+bh fold)

// composite-weight scratch (fp32, one-time)
__device__ float g_wcru[512 * 1024];         // Wy3 @ [Wxr_top | Wxu_top]
__device__ float g_wch[512 * 512];           // Wy3 @ Wxh_top
__device__ float g_bru[1024];                // br|bu + by3 @ Wx_top
__device__ float g_bh[512];                  // by3 @ Wxh_top

// Fragment-packed activation A buffer (bf16 hi + lo residual), NKT=96 k-tiles.
// col slabs: [0,512)=y2, [512,1024)=y2 dup, [1024,1536)=c, [1536,2048)=s,
//            [2048,2560)=r*s, [2560,3072)=y1
// idx = ((rt*96 + kt)*512) + ((kg*16 + r)*8) + j ; rt=b>>4, r=b&15,
// kt=col>>5, kg=(col>>3)&3, j=col&7
__device__ u16 g_ah[(size_t)8 * 96 * 512];
__device__ u16 g_al[(size_t)8 * 96 * 512];

// Fragment-packed bf16 weights: idx = ((ntile*NKT + kt)*512 + l*8 + j)
__device__ u16 Wy1p[(size_t)32 * 16 * 512];
__device__ u16 Wy2p[(size_t)32 * 16 * 512];
__device__ u16 Wy3p[(size_t)16 * 16 * 512];
__device__ u16 We1sp[(size_t)32 * 16 * 512];
// WRUp: N=1024 (r|u), K=2048: kt0-15=Wc_hi, 16-31=Wc_lo, 32-47=Wx_mid, 48-63=Wh
__device__ u16 WRUp[(size_t)64 * 64 * 512];
// WPp: N=512, K=1536: kt0-15=Wch_hi, 16-31=Wch_lo, 32-47=Wxh_mid
__device__ u16 WPp[(size_t)32 * 48 * 512];
// Whhp: N=512, K=512
__device__ u16 Whhp[(size_t)32 * 16 * 512];

__device__ u16 cby1[H_];
__device__ u16 cby2[H_];
__device__ u16 cby3[O_];
__device__ u16 cbe1[H_];
__device__ u16 cWe2[H_];

__device__ __forceinline__ void store_packed(int b, int col, float v) {
  u16 hi = f2bf(v);
  size_t idx = (((size_t)(b >> 4) * 96 + (col >> 5)) << 9) +
               ((((col >> 3) & 3) * 16 + (b & 15)) << 3) + (col & 7);
  g_ah[idx] = hi;
  g_al[idx] = f2bf(v - bf2f(hi));
}

#define DEF_CONV(NAME, ARR, N)                                     \
  __global__ void conv_##NAME(const float* __restrict__ s) {       \
    int i = blockIdx.x * 256 + threadIdx.x;                        \
    if (i < (N)) ARR[i] = f2bf(s[i]);                              \
  }

DEF_CONV(by1, cby1, H_)
DEF_CONV(by2, cby2, H_)
DEF_CONV(by3, cby3, O_)
DEF_CONV(be1, cbe1, H_)
DEF_CONV(We2, cWe2, H_)

__global__ void conv_h(const float* __restrict__ s) {
  size_t i = (size_t)blockIdx.x * 256 + threadIdx.x;
  g_hb[i] = f2bf(s[i]);
}

// ---- composite GEMM: C[MODE] = A(512x256,lda256) @ B(256x512,ldb512) ----
// MODE selects the __device__ destination INSIDE device code (host code must
// never take the address of a __device__ symbol — that was the r4-r7 abort).
template <int MODE>
__global__ void __launch_bounds__(256) fgemm_comp(const float* __restrict__ A,
                                                  const float* __restrict__ B) {
  float* C = (MODE == 0) ? g_wcru : (MODE == 1) ? (g_wcru + 512) : g_wch;
  const int ldc = (MODE == 2) ? 512 : 1024;
  __shared__ float Ast[32][72];
  __shared__ float Bs[32][72];
  const int tid = threadIdx.x;
  const int tx = tid & 15, ty = tid >> 4;
  const int n0 = blockIdx.x << 6;
  const int m0 = blockIdx.y << 6;
  float acc[4][4] = {};
  for (int k0 = 0; k0 < 256; k0 += 32) {
    {
      int row = tid >> 2, kq = (tid & 3) << 3;
      const float* src = A + (size_t)(m0 + row) * 256 + k0 + kq;
      float4 v0 = *(const float4*)src;
      float4 v1 = *(const float4*)(src + 4);
      Ast[kq + 0][row] = v0.x; Ast[kq + 1][row] = v0.y;
      Ast[kq + 2][row] = v0.z; Ast[kq + 3][row] = v0.w;
      Ast[kq + 4][row] = v1.x; Ast[kq + 5][row] = v1.y;
      Ast[kq + 6][row] = v1.z; Ast[kq + 7][row] = v1.w;
    }
    {
      int kr = tid >> 3, nq = (tid & 7) << 3;
      const float* src = B + (size_t)(k0 + kr) * 512 + n0 + nq;
      float4 v0 = *(const float4*)src;
      float4 v1 = *(const float4*)(src + 4);
      float* d = &Bs[kr][nq];
      d[0] = v0.x; d[1] = v0.y; d[2] = v0.z; d[3] = v0.w;
      d[4] = v1.x; d[5] = v1.y; d[6] = v1.z; d[7] = v1.w;
    }
    __syncthreads();
#pragma unroll
    for (int kk = 0; kk < 32; ++kk) {
      const float4 a4 = *(const float4*)&Ast[kk][ty << 2];
      const float4 b4 = *(const float4*)&Bs[kk][tx << 2];
      float av[4] = {a4.x, a4.y, a4.z, a4.w};
      float bv[4] = {b4.x, b4.y, b4.z, b4.w};
#pragma unroll
      for (int i = 0; i < 4; ++i)
#pragma unroll
        for (int j = 0; j < 4; ++j) acc[i][j] = fmaf(av[i], bv[j], acc[i][j]);
    }
    __syncthreads();
  }
#pragma unroll
  for (int i = 0; i < 4; ++i)
#pragma unroll
    for (int j = 0; j < 4; ++j)
      C[(size_t)(m0 + ty * 4 + i) * ldc + n0 + tx * 4 + j] = acc[i][j];
}

__global__ void bias_fold(const float* __restrict__ by3,
                          const float* __restrict__ Wxr,
                          const float* __restrict__ Wxu,
                          const float* __restrict__ br,
                          const float* __restrict__ bu,
                          const float* __restrict__ Wxh) {
  int n = blockIdx.x * 256 + threadIdx.x;
  if (n < 1024) {
    const float* W = (n < 512) ? Wxr : Wxu;
    int nn = n & 511;
    float acc = (n < 512) ? br[nn] : bu[nn];
    for (int k = 0; k < 256; ++k) acc += by3[k] * W[(size_t)k * 512 + nn];
    g_bru[n] = acc;
  } else if (n < 1536) {
    int nn = n - 1024;
    float acc = 0.f;
    for (int k = 0; k < 256; ++k) acc += by3[k] * Wxh[(size_t)k * 512 + nn];
    g_bh[nn] = acc;
  }
}

// ---- weight packers ----
#define DEF_PACKB(NAME, DST, NKT, SRCEXPR)                               \
  __global__ void NAME(const float* __restrict__ S0) {                   \
    int gid = blockIdx.x * 256 + threadIdx.x;                            \
    int l = gid & 63, kt = (gid >> 6) % (NKT);                           \
    int ntile = gid / (64 * (NKT));                                      \
    int n = ntile * 16 + (l & 15);                                       \
    __align__(16) u16 tmp[8];                                            \
    _Pragma("unroll")                                                    \
    for (int j = 0; j < 8; ++j) {                                        \
      int k = kt * 32 + ((l >> 4) << 3) + j;                             \
      tmp[j] = f2bf(SRCEXPR);                                            \
    }                                                                    \
    *(uint4*)(DST + (size_t)gid * 8) = *(const uint4*)tmp;               \
  }

DEF_PACKB(pack_Wy1, Wy1p, 16, S0[(size_t)k * 512 + n])
DEF_PACKB(pack_Wy2, Wy2p, 16, S0[(size_t)k * 512 + n])
DEF_PACKB(pack_Wy3, Wy3p, 16, S0[(size_t)k * 256 + n])
DEF_PACKB(pack_We1s, We1sp, 16, S0[(size_t)(512 + k) * 512 + n])

__global__ void pack_WRU(const float* __restrict__ Wxr, const float* __restrict__ Whr,
                         const float* __restrict__ Wxu, const float* __restrict__ Whu) {
  int gid = blockIdx.x * 256 + threadIdx.x;   // 64 ntile * 64 kt * 64 lanes
  int l = gid & 63, kt = (gid >> 6) & 63;
  int ntile = gid >> 12;
  int n = ntile * 16 + (l & 15);
  int nn = n & 511;
  __align__(16) u16 tmp[8];
#pragma unroll
  for (int j = 0; j < 8; ++j) {
    int k = kt * 32 + ((l >> 4) << 3) + j;   // 0..2047
    float v;
    if (k < 512) v = g_wcru[(size_t)k * 1024 + n];
    else if (k < 1024) {
      float x = g_wcru[(size_t)(k - 512) * 1024 + n];
      v = x - bf2f(f2bf(x));
    } else if (k < 1536) {
      v = (n < 512) ? Wxr[(size_t)(k - 1024 + 256) * 512 + nn]
                    : Wxu[(size_t)(k - 1024 + 256) * 512 + nn];
    } else {
      v = (n < 512) ? Whr[(size_t)(k - 1536) * 512 + nn]
                    : Whu[(size_t)(k - 1536) * 512 + nn];
    }
    tmp[j] = f2bf(v);
  }
  *(uint4*)(WRUp + (size_t)gid * 8) = *(const uint4*)tmp;
}

__global__ void pack_WP(const float* __restrict__ Wxh) {
  int gid = blockIdx.x * 256 + threadIdx.x;   // 32 ntile * 48 kt * 64 lanes
  int l = gid & 63, kt = (gid >> 6) % 48;
  int ntile = gid / (64 * 48);
  int n = ntile * 16 + (l & 15);
  __align__(16) u16 tmp[8];
#pragma unroll
  for (int j = 0; j < 8; ++j) {
    int k = kt * 32 + ((l >> 4) << 3) + j;   // 0..1535
    float v;
    if (k < 512) v = g_wch[(size_t)k * 512 + n];
    else if (k < 1024) {
      float x = g_wch[(size_t)(k - 512) * 512 + n];
      v = x - bf2f(f2bf(x));
    } else {
      v = Wxh[(size_t)(k - 1024 + 256) * 512 + n];
    }
    tmp[j] = f2bf(v);
  }
  *(uint4*)(WPp + (size_t)gid * 8) = *(const uint4*)tmp;
}

__global__ void pack_Whh(const float* __restrict__ Whh) {
  int gid = blockIdx.x * 256 + threadIdx.x;   // 32 ntile * 16 kt * 64 lanes
  int l = gid & 63, kt = (gid >> 6) & 15;
  int ntile = gid >> 10;
  int n = ntile * 16 + (l & 15);
  __align__(16) u16 tmp[8];
#pragma unroll
  for (int j = 0; j < 8; ++j) {
    int k = kt * 32 + ((l >> 4) << 3) + j;
    tmp[j] = f2bf(Whh[(size_t)k * 512 + n]);
  }
  *(uint4*)(Whhp + (size_t)gid * 8) = *(const uint4*)tmp;
}

__global__ void init_kernel(const float* __restrict__ s0) {
  int g = blockIdx.x * blockDim.x + threadIdx.x;
  if (g < B_ * H_) {
    float v = s0[g];
    g_s[g] = v;
    int b = g >> 9, n = g & 511;
    store_packed(b, 1536 + n, v);
  }
}

// ---- h_proj = h @ We1[:H]  (fp32 in, bf16 out) ----
__global__ void __launch_bounds__(256) hproj_kernel(const float* __restrict__ hh,
                                                    const float* __restrict__ We1) {
  __shared__ float Ast[32][72];
  __shared__ float Bs[32][72];
  const int tid = threadIdx.x;
  const int tx = tid & 15, ty = tid >> 4;
  const int n0 = blockIdx.x << 6;
  const int m0 = blockIdx.y << 6;
  float acc[4][4] = {};
  for (int k0 = 0; k0 < H_; k0 += 32) {
    {
      int row = tid >> 2, kq = (tid & 3) << 3;
      const float* src = hh + (size_t)(m0 + row) * H_ + k0 + kq;
      float4 v0 = *(const float4*)src;
      float4 v1 = *(const float4*)(src + 4);
      Ast[kq + 0][row] = v0.x; Ast[kq + 1][row] = v0.y;
      Ast[kq + 2][row] = v0.z; Ast[kq + 3][row] = v0.w;
      Ast[kq + 4][row] = v1.x; Ast[kq + 5][row] = v1.y;
      Ast[kq + 6][row] = v1.z; Ast[kq + 7][row] = v1.w;
    }
    {
      int kr = tid >> 3, nq = (tid & 7) << 3;
      const float* src = We1 + (size_t)(k0 + kr) * H_ + n0 + nq;
      float4 v0 = *(const float4*)src;
      float4 v1 = *(const float4*)(src + 4);
      float* d = &Bs[kr][nq];
      d[0] = v0.x; d[1] = v0.y; d[2] = v0.z; d[3] = v0.w;
      d[4] = v1.x; d[5] = v1.y; d[6] = v1.z; d[7] = v1.w;
    }
    __syncthreads();
#pragma unroll
    for (int kk = 0; kk < 32; ++kk) {
      const float4 a4 = *(const float4*)&Ast[kk][ty << 2];
      const float4 b4 = *(const float4*)&Bs[kk][tx << 2];
      float av[4] = {a4.x, a4.y, a4.z, a4.w};
      float bv[4] = {b4.x, b4.y, b4.z, b4.w};
#pragma unroll
      for (int i = 0; i < 4; ++i)
#pragma unroll
        for (int j = 0; j < 4; ++j) acc[i][j] = fmaf(av[i], bv[j], acc[i][j]);
    }
    __syncthreads();
  }
#pragma unroll
  for (int i = 0; i < 4; ++i) {
    u16* dst = g_hp + (size_t)(m0 + ty * 4 + i) * H_ + n0 + tx * 4;
    u32 w0 = (u32)f2bf(acc[i][0]) | ((u32)f2bf(acc[i][1]) << 16);
    u32 w1 = (u32)f2bf(acc[i][2]) | ((u32)f2bf(acc[i][3]) << 16);
    *(u32*)dst = w0;
    *(u32*)(dst + 2) = w1;
  }
}

#define FMA8(pk, sk, A)                                          \
  {                                                              \
    u32 ww0 = pk.x, ww1 = pk.y, ww2 = pk.z, ww3 = pk.w;          \
    A[0] = fmaf(sk, bf2f((u16)(ww0 & 0xffffu)), A[0]);           \
    A[1] = fmaf(sk, bf2f((u16)(ww0 >> 16)), A[1]);               \
    A[2] = fmaf(sk, bf2f((u16)(ww1 & 0xffffu)), A[2]);           \
    A[3] = fmaf(sk, bf2f((u16)(ww1 >> 16)), A[3]);               \
    A[4] = fmaf(sk, bf2f((u16)(ww2 & 0xffffu)), A[4]);           \
    A[5] = fmaf(sk, bf2f((u16)(ww2 >> 16)), A[5]);               \
    A[6] = fmaf(sk, bf2f((u16)(ww3 & 0xffffu)), A[6]);           \
    A[7] = fmaf(sk, bf2f((u16)(ww3 >> 16)), A[7]);               \
  }

// ---- GEMM core (M=16, N=64): 8-wave k-split, hi/lo A (k3 only) ----
template <int KTA0, int NKT_B, int KTW>
__device__ __forceinline__ void gemm_core(const u16* __restrict__ BP, int mt,
                                          int nb, int tid, float* smem) {
  const int l = tid & 63, w = tid >> 6;
  f32x4 acc0 = {0.f, 0.f, 0.f, 0.f}, acc1 = {0.f, 0.f, 0.f, 0.f};
  f32x4 acc2 = {0.f, 0.f, 0.f, 0.f}, acc3 = {0.f, 0.f, 0.f, 0.f};
  const size_t abase = (((size_t)mt * 96 + KTA0 + w * KTW) << 9) + l * 8;
#pragma unroll
  for (int kk = 0; kk < KTW; ++kk) {
    short8 ah = *(const short8*)(g_ah + abase + (size_t)kk * 512);
    short8 al = *(const short8*)(g_al + abase + (size_t)kk * 512);
    const size_t bbase =
        (((size_t)(nb * 4) * NKT_B + w * KTW + kk) << 9) + l * 8;
    short8 b0 = *(const short8*)(BP + bbase);
    short8 b1 = *(const short8*)(BP + bbase + ((size_t)NKT_B << 9));
    short8 b2 = *(const short8*)(BP + bbase + ((size_t)2 * NKT_B << 9));
    short8 b3 = *(const short8*)(BP + bbase + ((size_t)3 * NKT_B << 9));
    acc0 = __builtin_amdgcn_mfma_f32_16x16x32_bf16(ah, b0, acc0, 0, 0, 0);
    acc0 = __builtin_amdgcn_mfma_f32_16x16x32_bf16(al, b0, acc0, 0, 0, 0);
    acc1 = __builtin_amdgcn_mfma_f32_16x16x32_bf16(ah, b1, acc1, 0, 0, 0);
    acc1 = __builtin_amdgcn_mfma_f32_16x16x32_bf16(al, b1, acc1, 0, 0, 0);
    acc2 = __builtin_amdgcn_mfma_f32_16x16x32_bf16(ah, b2, acc2, 0, 0, 0);
    acc2 = __builtin_amdgcn_mfma_f32_16x16x32_bf16(al, b2, acc2, 0, 0, 0);
    acc3 = __builtin_amdgcn_mfma_f32_16x16x32_bf16(ah, b3, acc3, 0, 0, 0);
    acc3 = __builtin_amdgcn_mfma_f32_16x16x32_bf16(al, b3, acc3, 0, 0, 0);
  }
  float* pw = smem + w * 1024;
  const int r0 = (l >> 4) * 4, c0 = l & 15;
#pragma unroll
  for (int r = 0; r < 4; ++r) {
    pw[(r0 + r) * 64 + 0 + c0] = acc0[r];
    pw[(r0 + r) * 64 + 16 + c0] = acc1[r];
    pw[(r0 + r) * 64 + 32 + c0] = acc2[r];
    pw[(r0 + r) * 64 + 48 + c0] = acc3[r];
  }
  __syncthreads();
}

// ---- GEMM core (M=16, N=32): NW waves k-split, 2 ntiles — for wide grids ----
template <int KTA0, int NKT_B, int KTW, int NW>
__device__ __forceinline__ void gemm_n32(const u16* __restrict__ BP, int mt,
                                         int nb2, int tid, float* smem) {
  const int l = tid & 63, w = tid >> 6;   // w in [0, NW)
  f32x4 acc0 = {0.f, 0.f, 0.f, 0.f}, acc1 = {0.f, 0.f, 0.f, 0.f};
  const size_t abase = (((size_t)mt * 96 + KTA0 + w * KTW) << 9) + l * 8;
#pragma unroll
  for (int kk = 0; kk < KTW; ++kk) {
    short8 ah = *(const short8*)(g_ah + abase + (size_t)kk * 512);
    short8 al = *(const short8*)(g_al + abase + (size_t)kk * 512);
    const size_t bbase =
        (((size_t)(nb2 * 2) * NKT_B + w * KTW + kk) << 9) + l * 8;
    short8 b0 = *(const short8*)(BP + bbase);
    short8 b1 = *(const short8*)(BP + bbase + ((size_t)NKT_B << 9));
    acc0 = __builtin_amdgcn_mfma_f32_16x16x32_bf16(ah, b0, acc0, 0, 0, 0);
    acc0 = __builtin_amdgcn_mfma_f32_16x16x32_bf16(al, b0, acc0, 0, 0, 0);
    acc1 = __builtin_amdgcn_mfma_f32_16x16x32_bf16(ah, b1, acc1, 0, 0, 0);
    acc1 = __builtin_amdgcn_mfma_f32_16x16x32_bf16(al, b1, acc1, 0, 0, 0);
  }
  float* pw = smem + w * 512;
  const int r0 = (l >> 4) * 4, c0 = l & 15;
#pragma unroll
  for (int r = 0; r < 4; ++r) {
    pw[(r0 + r) * 32 + c0] = acc0[r];
    pw[(r0 + r) * 32 + 16 + c0] = acc1[r];
  }
  __syncthreads();
}

#define EPI_V64(row, col)                                            \
  float v = 0.f;                                                     \
  _Pragma("unroll") for (int ww = 0; ww < 8; ++ww)                   \
      v += smem[ww * 1024 + (row) * 64 + (col)];

#define EPI_V32(row, col, NW)                                        \
  float v = 0.f;                                                     \
  _Pragma("unroll") for (int ww = 0; ww < (NW); ++ww)                \
      v += smem[ww * 512 + (row) * 32 + (col)];

// ---- k1: y1 (0-127, N=32) || sp (128-255, N=32) — full-GPU grid ----
__global__ void __launch_bounds__(512) k1_y1sp() {
  __shared__ __align__(16) float smem[4096];
  const int tid = threadIdx.x;
  const int bid = blockIdx.x;
  if (bid < 128) {
    const int mt = bid >> 4, nb2 = bid & 15;
    gemm_n32<48, 16, 2, 8>(Wy1p, mt, nb2, tid, smem);
    int row = tid >> 5, col = tid & 31;
    EPI_V32(row, col, 8);
    int gb = mt * 16 + row, gc = nb2 * 32 + col;
    v += bf2f(cby1[gc]);
    store_packed(gb, 2560 + gc, ftanh(v));
  } else {
    const int blk2 = bid - 128;
    const int mt = blk2 >> 4, nb2 = blk2 & 15;
    gemm_n32<48, 16, 2, 8>(We1sp, mt, nb2, tid, smem);
    int row = tid >> 5, col = tid & 31;
    EPI_V32(row, col, 8);
    int gb = mt * 16 + row, gc = nb2 * 32 + col;
    g_sp[gb * H_ + gc] = v + bf2f(cbe1[gc]);
  }
}

// ---- k2: y2 (0-127, 16-wave N=32) || attn (128-255, 1024 thr) ----
__global__ void __launch_bounds__(1024) k2_y2attn() {
  __shared__ __align__(16) float smem[10240];
  __shared__ float red[32];
  const int tid = threadIdx.x;
  const int bid = blockIdx.x;
  if (bid < 128) {
    const int mt = bid >> 4, nb2 = bid & 15;
    gemm_n32<80, 16, 1, 16>(Wy2p, mt, nb2, tid, smem);
    if (tid < 512) {
      int row = tid >> 5, col = tid & 31;
      EPI_V32(row, col, 16);
      int gb = mt * 16 + row, gc = nb2 * 32 + col;
      v += bf2f(cby2[gc]);
      float y2v = ftanh(v);
      store_packed(gb, gc, y2v);
      store_packed(gb, 512 + gc, y2v);
    }
  } else {
    const int b = bid - 128;
    float* sm_e = smem + 1024;
    if (tid < 512) {
      float spv = g_sp[b * H_ + tid];
      float w2 = bf2f(cWe2[tid]);
      smem[2 * tid] = spv * TWOLOG2E_F;
      smem[2 * tid + 1] = -2.0f * w2;
    }
    __syncthreads();
    const int wv = tid >> 6, l = tid & 63;   // 16 waves
    const int rr = l & 15, q = l >> 4;
    {
      int tp = wv * 16 + rr;                 // one pass covers all 256 tp
      const u16* rowp = g_hp + ((size_t)(b * T_ + tp) << 9);
      float part = 0.f;
      for (int i = 0; i < 16; ++i) {
        int c0 = i * 32 + q * 8;
        uint4 pk = *(const uint4*)(rowp + c0);
        const float4* swp = reinterpret_cast<const float4*>(smem + 2 * c0);
        float4 f0 = swp[0], f1 = swp[1], f2 = swp[2], f3 = swp[3];
        u32 ww[4] = {pk.x, pk.y, pk.z, pk.w};
        {
          float h0 = bf2f((u16)(ww[0] & 0xffffu)), h1 = bf2f((u16)(ww[0] >> 16));
          float x0 = fmaf(h0, TWOLOG2E_F, f0.x);
          float x1 = fmaf(h1, TWOLOG2E_F, f0.z);
          part = fmaf(f0.y, RCPF(EXP2(x0) + 1.f), part);
          part = fmaf(f0.w, RCPF(EXP2(x1) + 1.f), part);
        }
        {
          float h0 = bf2f((u16)(ww[1] & 0xffffu)), h1 = bf2f((u16)(ww[1] >> 16));
          float x0 = fmaf(h0, TWOLOG2E_F, f1.x);
          float x1 = fmaf(h1, TWOLOG2E_F, f1.z);
          part = fmaf(f1.y, RCPF(EXP2(x0) + 1.f), part);
          part = fmaf(f1.w, RCPF(EXP2(x1) + 1.f), part);
        }
        {
          float h0 = bf2f((u16)(ww[2] & 0xffffu)), h1 = bf2f((u16)(ww[2] >> 16));
          float x0 = fmaf(h0, TWOLOG2E_F, f2.x);
          float x1 = fmaf(h1, TWOLOG2E_F, f2.z);
          part = fmaf(f2.y, RCPF(EXP2(x0) + 1.f), part);
          part = fmaf(f2.w, RCPF(EXP2(x1) + 1.f), part);
        }
        {
          float h0 = bf2f((u16)(ww[3] & 0xffffu)), h1 = bf2f((u16)(ww[3] >> 16));
          float x0 = fmaf(h0, TWOLOG2E_F, f3.x);
          float x1 = fmaf(h1, TWOLOG2E_F, f3.z);
          part = fmaf(f3.y, RCPF(EXP2(x0) + 1.f), part);
          part = fmaf(f3.w, RCPF(EXP2(x1) + 1.f), part);
        }
      }
      part += __shfl_xor(part, 16, 64);
      part += __shfl_xor(part, 32, 64);
      if (q == 0) sm_e[tp] = part;
    }
    __syncthreads();
    float v = (tid < T_) ? sm_e[tid] : -3.0e38f;
    float m = v;
#pragma unroll
    for (int off = 32; off > 0; off >>= 1) m = fmaxf(m, __shfl_xor(m, off, 64));
    if (l == 0) red[wv] = m;
    __syncthreads();
    m = red[0];
#pragma unroll
    for (int rI = 1; rI < 16; ++rI) m = fmaxf(m, red[rI]);
    float pe = (tid < T_) ? EXP2((v - m) * LOG2E_F) : 0.f;
    float ssum = pe;
#pragma unroll
    for (int off = 32; off > 0; off >>= 1) ssum += __shfl_xor(ssum, off, 64);
    if (l == 0) red[16 + wv] = ssum;
    __syncthreads();
    float tot = 0.f;
#pragma unroll
    for (int rI = 0; rI < 16; ++rI) tot += red[16 + rI];
    float ainv = RCPF(tot);
    if (tid < T_) sm_e[tid] = pe * ainv;
    __syncthreads();
    { // c = a @ h (16 tp-splits of 16)
      const int ts = tid >> 6, c = tid & 63, n0 = c << 3;
      float a[8] = {};
      for (int tp = ts * 16; tp < ts * 16 + 16; ++tp) {
        uint4 pk = *(const uint4*)(g_hb + ((size_t)(b * T_ + tp) << 9) + n0);
        float av = sm_e[tp];
        FMA8(pk, av, a);
      }
      float* pt = smem + 1536 + ts * 512 + n0;
#pragma unroll
      for (int j = 0; j < 8; ++j) pt[j] = a[j];
    }
    __syncthreads();
    if (tid < 512) {
      float v2 = 0.f;
#pragma unroll
      for (int kk = 0; kk < 16; ++kk) v2 += smem[1536 + kk * 512 + tid];
      store_packed(b, 1024 + tid, v2);
    }
  }
}

// ---- k3: y3out (0-31) || RU (32-159) || P (160-223) — unchanged r8 ----
__global__ void __launch_bounds__(512) k3_y3rup(float* __restrict__ out, int t) {
  __shared__ __align__(16) float smem[8192];
  const int tid = threadIdx.x;
  const int bid = blockIdx.x;
  if (bid < 32) {
    const int mt3 = bid >> 2, nb3 = bid & 3;
    gemm_core<0, 16, 2>(Wy3p, mt3, nb3, tid, smem);
#pragma unroll
    for (int rep = 0; rep < 2; ++rep) {
      int idx = rep * 512 + tid, row = idx >> 6, col = idx & 63;
      EPI_V64(row, col);
      int gb = mt3 * 16 + row, gc = nb3 * 64 + col;
      v += bf2f(cby3[gc]);
      out[((size_t)gb * T_ + t) * O_ + gc] = v;
    }
  } else if (bid < 160) {
    const int idx2 = bid - 32;
    const int mt = idx2 >> 4, nbz = idx2 & 15;
    gemm_core<0, 64, 8>(WRUp, mt, nbz, tid, smem);
#pragma unroll
    for (int rep = 0; rep < 2; ++rep) {
      int idx = rep * 512 + tid, row = idx >> 6, col = idx & 63;
      EPI_V64(row, col);
      int gb = mt * 16 + row, gc = nbz * 64 + col;
      v += g_bru[gc];
      if (gc < 512) {
        float rv = fsigm(v);
        float rs = rv * g_s[gb * H_ + gc];
        store_packed(gb, 2048 + gc, rs);
      } else {
        g_u[gb * H_ + (gc - 512)] = fsigm(v);
      }
    }
  } else {
    const int idx2 = bid - 160;
    const int mt = idx2 >> 3, nb = idx2 & 7;
    gemm_core<0, 48, 6>(WPp, mt, nb, tid, smem);
#pragma unroll
    for (int rep = 0; rep < 2; ++rep) {
      int idx = rep * 512 + tid, row = idx >> 6, col = idx & 63;
      EPI_V64(row, col);
      int gb = mt * 16 + row, gc = nb * 64 + col;
      g_p[gb * H_ + gc] = v + g_bh[gc];
    }
  }
}

// ---- k4: HC + s-update (128 blocks, N=32 — full-width) ----
__global__ void __launch_bounds__(512) k4_hc() {
  __shared__ __align__(16) float smem[4096];
  const int tid = threadIdx.x;
  const int bid = blockIdx.x;
  const int mt = bid >> 4, nb2 = bid & 15;
  gemm_n32<64, 16, 2, 8>(Whhp, mt, nb2, tid, smem);
  int row = tid >> 5, col = tid & 31;
  EPI_V32(row, col, 8);
  int gb = mt * 16 + row, gc = nb2 * 32 + col;
  int sidx = gb * H_ + gc;
  v += g_p[sidx];
  float hc = ftanh(v);
  float uu = g_u[sidx];
  float sn = (1.f - uu) * hc + uu * g_s[sidx];
  g_s[sidx] = sn;
  store_packed(gb, 1536 + gc, sn);
}

extern "C" void kernel_launch(void* const* d_in, const int* in_sizes, int n_in,
                              void* d_out, int out_size, void* d_ws, size_t ws_size,
                              hipStream_t stream) {
  (void)in_sizes; (void)n_in; (void)out_size; (void)d_ws; (void)ws_size;
  const float* h = (const float*)d_in[0];
  float* out = (float*)d_out;

#define CONV(NAME, IDX, N) \
  hipLaunchKernelGGL(conv_##NAME, dim3(((N) + 255) / 256), dim3(256), 0, stream, \
                     (const float*)d_in[IDX])
  CONV(by1, 3, H_);
  CONV(by2, 5, H_);
  CONV(by3, 7, O_);
  CONV(be1, 9, H_);
  CONV(We2, 10, H_);
  // d_in[11] = be2: softmax shift-invariant, unused
#undef CONV
  // composite weights: destinations selected in device code (never pass
  // __device__ symbols as host-side kernel args — r4-r7 abort cause)
  hipLaunchKernelGGL((fgemm_comp<0>), dim3(8, 8), dim3(256), 0, stream,
                     (const float*)d_in[6], (const float*)d_in[12]);
  hipLaunchKernelGGL((fgemm_comp<1>), dim3(8, 8), dim3(256), 0, stream,
                     (const float*)d_in[6], (const float*)d_in[15]);
  hipLaunchKernelGGL((fgemm_comp<2>), dim3(8, 8), dim3(256), 0, stream,
                     (const float*)d_in[6], (const float*)d_in[18]);
  hipLaunchKernelGGL(bias_fold, dim3(6), dim3(256), 0, stream,
                     (const float*)d_in[7], (const float*)d_in[12],
                     (const float*)d_in[15], (const float*)d_in[14],
                     (const float*)d_in[17], (const float*)d_in[18]);
  hipLaunchKernelGGL(pack_Wy1, dim3(128), dim3(256), 0, stream, (const float*)d_in[2]);
  hipLaunchKernelGGL(pack_Wy2, dim3(128), dim3(256), 0, stream, (const float*)d_in[4]);
  hipLaunchKernelGGL(pack_Wy3, dim3(64), dim3(256), 0, stream, (const float*)d_in[6]);
  hipLaunchKernelGGL(pack_We1s, dim3(128), dim3(256), 0, stream, (const float*)d_in[8]);
  hipLaunchKernelGGL(pack_WRU, dim3(1024), dim3(256), 0, stream,
                     (const float*)d_in[12], (const float*)d_in[13],
                     (const float*)d_in[15], (const float*)d_in[16]);
  hipLaunchKernelGGL(pack_WP, dim3(384), dim3(256), 0, stream,
                     (const float*)d_in[18]);
  hipLaunchKernelGGL(pack_Whh, dim3(128), dim3(256), 0, stream,
                     (const float*)d_in[19]);
  hipLaunchKernelGGL(conv_h, dim3((B_ * T_ * H_) / 256), dim3(256), 0, stream, h);
  hipLaunchKernelGGL(init_kernel, dim3(256), dim3(256), 0, stream,
                     (const float*)d_in[1]);
  hipLaunchKernelGGL(hproj_kernel, dim3(8, 512), dim3(256), 0, stream, h,
                     (const float*)d_in[8]);

  for (int t = 0; t < T_; ++t) {
    hipLaunchKernelGGL(k1_y1sp, dim3(256), dim3(512), 0, stream);
    hipLaunchKernelGGL(k2_y2attn, dim3(256), dim3(1024), 0, stream);
    hipLaunchKernelGGL(k3_y3rup, dim3(224), dim3(512), 0, stream, out, t);
    hipLaunchKernelGGL(k4_hc, dim3(128), dim3(512), 0, stream);
  }
}

// Round 12
// 8325.741 us; speedup vs baseline: 17.2186x; 1.0387x over previous
//
#include <hip/hip_runtime.h>

#define B_ 128
#define T_ 256
#define H_ 512
#define O_ 256
#define X_ 768

typedef unsigned short u16;
typedef unsigned int u32;

#if __has_builtin(__builtin_amdgcn_exp2f)
#define EXP2(x) __builtin_amdgcn_exp2f(x)
#else
#define EXP2(x) exp2f(x)
#endif
#if __has_builtin(__builtin_amdgcn_rcpf)
#define RCPF(x) __builtin_amdgcn_rcpf(x)
#else
#define RCPF(x) (1.0f / (x))
#endif

#define LOG2E_F 1.4426950408889634f
#define TWOLOG2E_F 2.8853900817779268f

typedef __attribute__((ext_vector_type(8))) short short8;
typedef __attribute__((ext_vector_type(4))) float f32x4;

__device__ __forceinline__ float bf2f(u16 v) {
  union { u32 u; float f; } c; c.u = ((u32)v) << 16; return c.f;
}
__device__ __forceinline__ u16 f2bf(float f) {
  union { float f; u32 u; } c; c.f = f;
  return (u16)((c.u + 0x7FFFu + ((c.u >> 16) & 1u)) >> 16);
}
__device__ __forceinline__ float ftanh(float x) {
  x = fminf(fmaxf(x, -40.f), 40.f);
  float z = EXP2(x * TWOLOG2E_F);
  return (z - 1.0f) * RCPF(z + 1.0f);
}
__device__ __forceinline__ float fsigm(float x) {
  x = fminf(fmaxf(x, -40.f), 40.f);
  return RCPF(1.0f + EXP2(-x * LOG2E_F));
}

// ---- module-scope scratch ----
__device__ u16 g_hp[(size_t)B_ * T_ * H_];   // bf16 h_proj
__device__ u16 g_hb[(size_t)B_ * T_ * H_];   // bf16 copy of h
__device__ float g_s[B_ * H_];               // fp32 state
__device__ float g_u[B_ * H_];
__device__ float g_sp[B_ * H_];              // s @ We1_s + be1
__device__ float g_p[B_ * H_];               // [y2,y2,c] @ WP (+bh fold)

// composite-weight scratch (fp32, one-time)
__device__ float g_wcru[512 * 1024];         // Wy3 @ [Wxr_top | Wxu_top]
__device__ float g_wch[512 * 512];           // Wy3 @ Wxh_top
__device__ float g_bru[1024];                // br|bu + by3 @ Wx_top
__device__ float g_bh[512];                  // by3 @ Wxh_top

// Fragment-packed activation A buffer (bf16 hi + lo residual), NKT=96 k-tiles.
// col slabs: [0,512)=y2, [512,1024)=y2 dup, [1024,1536)=c, [1536,2048)=s,
//            [2048,2560)=r*s, [2560,3072)=y1
// idx = ((rt*96 + kt)*512) + ((kg*16 + r)*8) + j ; rt=b>>4, r=b&15,
// kt=col>>5, kg=(col>>3)&3, j=col&7
__device__ u16 g_ah[(size_t)8 * 96 * 512];
__device__ u16 g_al[(size_t)8 * 96 * 512];

// Fragment-packed bf16 weights: idx = ((ntile*NKT + kt)*512 + l*8 + j)
__device__ u16 Wy1p[(size_t)32 * 16 * 512];
__device__ u16 Wy2p[(size_t)32 * 16 * 512];
__device__ u16 Wy3p[(size_t)16 * 16 * 512];
__device__ u16 We1sp[(size_t)32 * 16 * 512];
// WRUp: N=1024 (r|u), K=2048: kt0-15=Wc_hi, 16-31=Wc_lo, 32-47=Wx_mid, 48-63=Wh
__device__ u16 WRUp[(size_t)64 * 64 * 512];
// WPp: N=512, K=1536: kt0-15=Wch_hi, 16-31=Wch_lo, 32-47=Wxh_mid
__device__ u16 WPp[(size_t)32 * 48 * 512];
// Whhp: N=512, K=512
__device__ u16 Whhp[(size_t)32 * 16 * 512];

__device__ u16 cby1[H_];
__device__ u16 cby2[H_];
__device__ u16 cby3[O_];
__device__ u16 cbe1[H_];
__device__ u16 cWe2[H_];

__device__ __forceinline__ void store_packed(int b, int col, float v) {
  u16 hi = f2bf(v);
  size_t idx = (((size_t)(b >> 4) * 96 + (col >> 5)) << 9) +
               ((((col >> 3) & 3) * 16 + (b & 15)) << 3) + (col & 7);
  g_ah[idx] = hi;
  g_al[idx] = f2bf(v - bf2f(hi));
}

#define DEF_CONV(NAME, ARR, N)                                     \
  __global__ void conv_##NAME(const float* __restrict__ s) {       \
    int i = blockIdx.x * 256 + threadIdx.x;                        \
    if (i < (N)) ARR[i] = f2bf(s[i]);                              \
  }

DEF_CONV(by1, cby1, H_)
DEF_CONV(by2, cby2, H_)
DEF_CONV(by3, cby3, O_)
DEF_CONV(be1, cbe1, H_)
DEF_CONV(We2, cWe2, H_)

__global__ void conv_h(const float* __restrict__ s) {
  size_t i = (size_t)blockIdx.x * 256 + threadIdx.x;
  g_hb[i] = f2bf(s[i]);
}

// ---- composite GEMM: C[MODE] = A(512x256,lda256) @ B(256x512,ldb512) ----
// MODE selects the __device__ destination INSIDE device code (host code must
// never take the address of a __device__ symbol — that was the r4-r7 abort).
template <int MODE>
__global__ void __launch_bounds__(256) fgemm_comp(const float* __restrict__ A,
                                                  const float* __restrict__ B) {
  float* C = (MODE == 0) ? g_wcru : (MODE == 1) ? (g_wcru + 512) : g_wch;
  const int ldc = (MODE == 2) ? 512 : 1024;
  __shared__ float Ast[32][72];
  __shared__ float Bs[32][72];
  const int tid = threadIdx.x;
  const int tx = tid & 15, ty = tid >> 4;
  const int n0 = blockIdx.x << 6;
  const int m0 = blockIdx.y << 6;
  float acc[4][4] = {};
  for (int k0 = 0; k0 < 256; k0 += 32) {
    {
      int row = tid >> 2, kq = (tid & 3) << 3;
      const float* src = A + (size_t)(m0 + row) * 256 + k0 + kq;
      float4 v0 = *(const float4*)src;
      float4 v1 = *(const float4*)(src + 4);
      Ast[kq + 0][row] = v0.x; Ast[kq + 1][row] = v0.y;
      Ast[kq + 2][row] = v0.z; Ast[kq + 3][row] = v0.w;
      Ast[kq + 4][row] = v1.x; Ast[kq + 5][row] = v1.y;
      Ast[kq + 6][row] = v1.z; Ast[kq + 7][row] = v1.w;
    }
    {
      int kr = tid >> 3, nq = (tid & 7) << 3;
      const float* src = B + (size_t)(k0 + kr) * 512 + n0 + nq;
      float4 v0 = *(const float4*)src;
      float4 v1 = *(const float4*)(src + 4);
      float* d = &Bs[kr][nq];
      d[0] = v0.x; d[1] = v0.y; d[2] = v0.z; d[3] = v0.w;
      d[4] = v1.x; d[5] = v1.y; d[6] = v1.z; d[7] = v1.w;
    }
    __syncthreads();
#pragma unroll
    for (int kk = 0; kk < 32; ++kk) {
      const float4 a4 = *(const float4*)&Ast[kk][ty << 2];
      const float4 b4 = *(const float4*)&Bs[kk][tx << 2];
      float av[4] = {a4.x, a4.y, a4.z, a4.w};
      float bv[4] = {b4.x, b4.y, b4.z, b4.w};
#pragma unroll
      for (int i = 0; i < 4; ++i)
#pragma unroll
        for (int j = 0; j < 4; ++j) acc[i][j] = fmaf(av[i], bv[j], acc[i][j]);
    }
    __syncthreads();
  }
#pragma unroll
  for (int i = 0; i < 4; ++i)
#pragma unroll
    for (int j = 0; j < 4; ++j)
      C[(size_t)(m0 + ty * 4 + i) * ldc + n0 + tx * 4 + j] = acc[i][j];
}

__global__ void bias_fold(const float* __restrict__ by3,
                          const float* __restrict__ Wxr,
                          const float* __restrict__ Wxu,
                          const float* __restrict__ br,
                          const float* __restrict__ bu,
                          const float* __restrict__ Wxh) {
  int n = blockIdx.x * 256 + threadIdx.x;
  if (n < 1024) {
    const float* W = (n < 512) ? Wxr : Wxu;
    int nn = n & 511;
    float acc = (n < 512) ? br[nn] : bu[nn];
    for (int k = 0; k < 256; ++k) acc += by3[k] * W[(size_t)k * 512 + nn];
    g_bru[n] = acc;
  } else if (n < 1536) {
    int nn = n - 1024;
    float acc = 0.f;
    for (int k = 0; k < 256; ++k) acc += by3[k] * Wxh[(size_t)k * 512 + nn];
    g_bh[nn] = acc;
  }
}

// ---- weight packers ----
#define DEF_PACKB(NAME, DST, NKT, SRCEXPR)                               \
  __global__ void NAME(const float* __restrict__ S0) {                   \
    int gid = blockIdx.x * 256 + threadIdx.x;                            \
    int l = gid & 63, kt = (gid >> 6) % (NKT);                           \
    int ntile = gid / (64 * (NKT));                                      \
    int n = ntile * 16 + (l & 15);                                       \
    __align__(16) u16 tmp[8];                                            \
    _Pragma("unroll")                                                    \
    for (int j = 0; j < 8; ++j) {                                        \
      int k = kt * 32 + ((l >> 4) << 3) + j;                             \
      tmp[j] = f2bf(SRCEXPR);                                            \
    }                                                                    \
    *(uint4*)(DST + (size_t)gid * 8) = *(const uint4*)tmp;               \
  }

DEF_PACKB(pack_Wy1, Wy1p, 16, S0[(size_t)k * 512 + n])
DEF_PACKB(pack_Wy2, Wy2p, 16, S0[(size_t)k * 512 + n])
DEF_PACKB(pack_Wy3, Wy3p, 16, S0[(size_t)k * 256 + n])
DEF_PACKB(pack_We1s, We1sp, 16, S0[(size_t)(512 + k) * 512 + n])

__global__ void pack_WRU(const float* __restrict__ Wxr, const float* __restrict__ Whr,
                         const float* __restrict__ Wxu, const float* __restrict__ Whu) {
  int gid = blockIdx.x * 256 + threadIdx.x;   // 64 ntile * 64 kt * 64 lanes
  int l = gid & 63, kt = (gid >> 6) & 63;
  int ntile = gid >> 12;
  int n = ntile * 16 + (l & 15);
  int nn = n & 511;
  __align__(16) u16 tmp[8];
#pragma unroll
  for (int j = 0; j < 8; ++j) {
    int k = kt * 32 + ((l >> 4) << 3) + j;   // 0..2047
    float v;
    if (k < 512) v = g_wcru[(size_t)k * 1024 + n];
    else if (k < 1024) {
      float x = g_wcru[(size_t)(k - 512) * 1024 + n];
      v = x - bf2f(f2bf(x));
    } else if (k < 1536) {
      v = (n < 512) ? Wxr[(size_t)(k - 1024 + 256) * 512 + nn]
                    : Wxu[(size_t)(k - 1024 + 256) * 512 + nn];
    } else {
      v = (n < 512) ? Whr[(size_t)(k - 1536) * 512 + nn]
                    : Whu[(size_t)(k - 1536) * 512 + nn];
    }
    tmp[j] = f2bf(v);
  }
  *(uint4*)(WRUp + (size_t)gid * 8) = *(const uint4*)tmp;
}

__global__ void pack_WP(const float* __restrict__ Wxh) {
  int gid = blockIdx.x * 256 + threadIdx.x;   // 32 ntile * 48 kt * 64 lanes
  int l = gid & 63, kt = (gid >> 6) % 48;
  int ntile = gid / (64 * 48);
  int n = ntile * 16 + (l & 15);
  __align__(16) u16 tmp[8];
#pragma unroll
  for (int j = 0; j < 8; ++j) {
    int k = kt * 32 + ((l >> 4) << 3) + j;   // 0..1535
    float v;
    if (k < 512) v = g_wch[(size_t)k * 512 + n];
    else if (k < 1024) {
      float x = g_wch[(size_t)(k - 512) * 512 + n];
      v = x - bf2f(f2bf(x));
    } else {
      v = Wxh[(size_t)(k - 1024 + 256) * 512 + n];
    }
    tmp[j] = f2bf(v);
  }
  *(uint4*)(WPp + (size_t)gid * 8) = *(const uint4*)tmp;
}

__global__ void pack_Whh(const float* __restrict__ Whh) {
  int gid = blockIdx.x * 256 + threadIdx.x;   // 32 ntile * 16 kt * 64 lanes
  int l = gid & 63, kt = (gid >> 6) & 15;
  int ntile = gid >> 10;
  int n = ntile * 16 + (l & 15);
  __align__(16) u16 tmp[8];
#pragma unroll
  for (int j = 0; j < 8; ++j) {
    int k = kt * 32 + ((l >> 4) << 3) + j;
    tmp[j] = f2bf(Whh[(size_t)k * 512 + n]);
  }
  *(uint4*)(Whhp + (size_t)gid * 8) = *(const uint4*)tmp;
}

__global__ void init_kernel(const float* __restrict__ s0) {
  int g = blockIdx.x * blockDim.x + threadIdx.x;
  if (g < B_ * H_) {
    float v = s0[g];
    g_s[g] = v;
    int b = g >> 9, n = g & 511;
    store_packed(b, 1536 + n, v);
  }
}

// ---- h_proj = h @ We1[:H]  (fp32 in, bf16 out) ----
__global__ void __launch_bounds__(256) hproj_kernel(const float* __restrict__ hh,
                                                    const float* __restrict__ We1) {
  __shared__ float Ast[32][72];
  __shared__ float Bs[32][72];
  const int tid = threadIdx.x;
  const int tx = tid & 15, ty = tid >> 4;
  const int n0 = blockIdx.x << 6;
  const int m0 = blockIdx.y << 6;
  float acc[4][4] = {};
  for (int k0 = 0; k0 < H_; k0 += 32) {
    {
      int row = tid >> 2, kq = (tid & 3) << 3;
      const float* src = hh + (size_t)(m0 + row) * H_ + k0 + kq;
      float4 v0 = *(const float4*)src;
      float4 v1 = *(const float4*)(src + 4);
      Ast[kq + 0][row] = v0.x; Ast[kq + 1][row] = v0.y;
      Ast[kq + 2][row] = v0.z; Ast[kq + 3][row] = v0.w;
      Ast[kq + 4][row] = v1.x; Ast[kq + 5][row] = v1.y;
      Ast[kq + 6][row] = v1.z; Ast[kq + 7][row] = v1.w;
    }
    {
      int kr = tid >> 3, nq = (tid & 7) << 3;
      const float* src = We1 + (size_t)(k0 + kr) * H_ + n0 + nq;
      float4 v0 = *(const float4*)src;
      float4 v1 = *(const float4*)(src + 4);
      float* d = &Bs[kr][nq];
      d[0] = v0.x; d[1] = v0.y; d[2] = v0.z; d[3] = v0.w;
      d[4] = v1.x; d[5] = v1.y; d[6] = v1.z; d[7] = v1.w;
    }
    __syncthreads();
#pragma unroll
    for (int kk = 0; kk < 32; ++kk) {
      const float4 a4 = *(const float4*)&Ast[kk][ty << 2];
      const float4 b4 = *(const float4*)&Bs[kk][tx << 2];
      float av[4] = {a4.x, a4.y, a4.z, a4.w};
      float bv[4] = {b4.x, b4.y, b4.z, b4.w};
#pragma unroll
      for (int i = 0; i < 4; ++i)
#pragma unroll
        for (int j = 0; j < 4; ++j) acc[i][j] = fmaf(av[i], bv[j], acc[i][j]);
    }
    __syncthreads();
  }
#pragma unroll
  for (int i = 0; i < 4; ++i) {
    u16* dst = g_hp + (size_t)(m0 + ty * 4 + i) * H_ + n0 + tx * 4;
    u32 w0 = (u32)f2bf(acc[i][0]) | ((u32)f2bf(acc[i][1]) << 16);
    u32 w1 = (u32)f2bf(acc[i][2]) | ((u32)f2bf(acc[i][3]) << 16);
    *(u32*)dst = w0;
    *(u32*)(dst + 2) = w1;
  }
}

#define FMA8(pk, sk, A)                                          \
  {                                                              \
    u32 ww0 = pk.x, ww1 = pk.y, ww2 = pk.z, ww3 = pk.w;          \
    A[0] = fmaf(sk, bf2f((u16)(ww0 & 0xffffu)), A[0]);           \
    A[1] = fmaf(sk, bf2f((u16)(ww0 >> 16)), A[1]);               \
    A[2] = fmaf(sk, bf2f((u16)(ww1 & 0xffffu)), A[2]);           \
    A[3] = fmaf(sk, bf2f((u16)(ww1 >> 16)), A[3]);               \
    A[4] = fmaf(sk, bf2f((u16)(ww2 & 0xffffu)), A[4]);           \
    A[5] = fmaf(sk, bf2f((u16)(ww2 >> 16)), A[5]);               \
    A[6] = fmaf(sk, bf2f((u16)(ww3 & 0xffffu)), A[6]);           \
    A[7] = fmaf(sk, bf2f((u16)(ww3 >> 16)), A[7]);               \
  }

// ---- generalized GEMM core: M=16, N=NT*16, NW waves k-split, hi/lo A ----
// covers kt range [KTA0, KTA0 + NW*KTW); B k-range [0, NW*KTW) of NKT_B
template <int KTA0, int NKT_B, int KTW, int NW, int NT>
__device__ __forceinline__ void gemm_w(const u16* __restrict__ BP, int mt,
                                       int nbt, int tid, float* smem) {
  const int l = tid & 63, w = tid >> 6;   // w in [0, NW)
  f32x4 acc[NT];
#pragma unroll
  for (int nt = 0; nt < NT; ++nt) acc[nt] = (f32x4){0.f, 0.f, 0.f, 0.f};
  const size_t abase = (((size_t)mt * 96 + KTA0 + w * KTW) << 9) + l * 8;
#pragma unroll
  for (int kk = 0; kk < KTW; ++kk) {
    short8 ah = *(const short8*)(g_ah + abase + (size_t)kk * 512);
    short8 al = *(const short8*)(g_al + abase + (size_t)kk * 512);
    const size_t bbase =
        (((size_t)(nbt * NT) * NKT_B + w * KTW + kk) << 9) + l * 8;
#pragma unroll
    for (int nt = 0; nt < NT; ++nt) {
      short8 bb = *(const short8*)(BP + bbase + (((size_t)nt * NKT_B) << 9));
      acc[nt] = __builtin_amdgcn_mfma_f32_16x16x32_bf16(ah, bb, acc[nt], 0, 0, 0);
      acc[nt] = __builtin_amdgcn_mfma_f32_16x16x32_bf16(al, bb, acc[nt], 0, 0, 0);
    }
  }
  float* pw = smem + w * (NT * 256);
  const int r0 = (l >> 4) * 4, c0 = l & 15;
#pragma unroll
  for (int r = 0; r < 4; ++r)
#pragma unroll
    for (int nt = 0; nt < NT; ++nt)
      pw[(r0 + r) * (NT * 16) + nt * 16 + c0] = acc[nt][r];
  __syncthreads();
}

#define EPI_W(row, col, NW, NT)                                      \
  float v = 0.f;                                                     \
  _Pragma("unroll") for (int ww = 0; ww < (NW); ++ww)                \
      v += smem[ww * ((NT) * 256) + (row) * ((NT) * 16) + (col)];

// ---- k1: y1 (0-127) || sp (128-255) — 1024 thr, 16-wave, N=32 ----
__global__ void __launch_bounds__(1024) k1_y1sp() {
  __shared__ __align__(16) float smem[8192];
  const int tid = threadIdx.x;
  const int bid = blockIdx.x;
  if (bid < 128) {
    const int mt = bid >> 4, nbt = bid & 15;
    gemm_w<48, 16, 1, 16, 2>(Wy1p, mt, nbt, tid, smem);
    if (tid < 512) {
      int row = tid >> 5, col = tid & 31;
      EPI_W(row, col, 16, 2);
      int gb = mt * 16 + row, gc = nbt * 32 + col;
      v += bf2f(cby1[gc]);
      store_packed(gb, 2560 + gc, ftanh(v));
    }
  } else {
    const int blk2 = bid - 128;
    const int mt = blk2 >> 4, nbt = blk2 & 15;
    gemm_w<48, 16, 1, 16, 2>(We1sp, mt, nbt, tid, smem);
    if (tid < 512) {
      int row = tid >> 5, col = tid & 31;
      EPI_W(row, col, 16, 2);
      int gb = mt * 16 + row, gc = nbt * 32 + col;
      g_sp[gb * H_ + gc] = v + bf2f(cbe1[gc]);
    }
  }
}

// ---- k2: y2 (0-127, 16-wave N=32) || attn (128-255, 1024 thr) ----
__global__ void __launch_bounds__(1024) k2_y2attn() {
  __shared__ __align__(16) float smem[10240];
  __shared__ float red[32];
  const int tid = threadIdx.x;
  const int bid = blockIdx.x;
  if (bid < 128) {
    const int mt = bid >> 4, nbt = bid & 15;
    gemm_w<80, 16, 1, 16, 2>(Wy2p, mt, nbt, tid, smem);
    if (tid < 512) {
      int row = tid >> 5, col = tid & 31;
      EPI_W(row, col, 16, 2);
      int gb = mt * 16 + row, gc = nbt * 32 + col;
      v += bf2f(cby2[gc]);
      float y2v = ftanh(v);
      store_packed(gb, gc, y2v);
      store_packed(gb, 512 + gc, y2v);
    }
  } else {
    const int b = bid - 128;
    float* sm_e = smem + 1024;
    if (tid < 512) {
      float spv = g_sp[b * H_ + tid];
      float w2 = bf2f(cWe2[tid]);
      smem[2 * tid] = spv * TWOLOG2E_F;
      smem[2 * tid + 1] = -2.0f * w2;
    }
    __syncthreads();
    const int wv = tid >> 6, l = tid & 63;   // 16 waves
    const int rr = l & 15, q = l >> 4;
    {
      int tp = wv * 16 + rr;                 // one pass covers all 256 tp
      const u16* rowp = g_hp + ((size_t)(b * T_ + tp) << 9);
      float part = 0.f;
      for (int i = 0; i < 16; ++i) {
        int c0 = i * 32 + q * 8;
        uint4 pk = *(const uint4*)(rowp + c0);
        const float4* swp = reinterpret_cast<const float4*>(smem + 2 * c0);
        float4 f0 = swp[0], f1 = swp[1], f2 = swp[2], f3 = swp[3];
        u32 ww[4] = {pk.x, pk.y, pk.z, pk.w};
        {
          float h0 = bf2f((u16)(ww[0] & 0xffffu)), h1 = bf2f((u16)(ww[0] >> 16));
          float x0 = fmaf(h0, TWOLOG2E_F, f0.x);
          float x1 = fmaf(h1, TWOLOG2E_F, f0.z);
          part = fmaf(f0.y, RCPF(EXP2(x0) + 1.f), part);
          part = fmaf(f0.w, RCPF(EXP2(x1) + 1.f), part);
        }
        {
          float h0 = bf2f((u16)(ww[1] & 0xffffu)), h1 = bf2f((u16)(ww[1] >> 16));
          float x0 = fmaf(h0, TWOLOG2E_F, f1.x);
          float x1 = fmaf(h1, TWOLOG2E_F, f1.z);
          part = fmaf(f1.y, RCPF(EXP2(x0) + 1.f), part);
          part = fmaf(f1.w, RCPF(EXP2(x1) + 1.f), part);
        }
        {
          float h0 = bf2f((u16)(ww[2] & 0xffffu)), h1 = bf2f((u16)(ww[2] >> 16));
          float x0 = fmaf(h0, TWOLOG2E_F, f2.x);
          float x1 = fmaf(h1, TWOLOG2E_F, f2.z);
          part = fmaf(f2.y, RCPF(EXP2(x0) + 1.f), part);
          part = fmaf(f2.w, RCPF(EXP2(x1) + 1.f), part);
        }
        {
          float h0 = bf2f((u16)(ww[3] & 0xffffu)), h1 = bf2f((u16)(ww[3] >> 16));
          float x0 = fmaf(h0, TWOLOG2E_F, f3.x);
          float x1 = fmaf(h1, TWOLOG2E_F, f3.z);
          part = fmaf(f3.y, RCPF(EXP2(x0) + 1.f), part);
          part = fmaf(f3.w, RCPF(EXP2(x1) + 1.f), part);
        }
      }
      part += __shfl_xor(part, 16, 64);
      part += __shfl_xor(part, 32, 64);
      if (q == 0) sm_e[tp] = part;
    }
    __syncthreads();
    float v = (tid < T_) ? sm_e[tid] : -3.0e38f;
    float m = v;
#pragma unroll
    for (int off = 32; off > 0; off >>= 1) m = fmaxf(m, __shfl_xor(m, off, 64));
    if (l == 0) red[wv] = m;
    __syncthreads();
    m = red[0];
#pragma unroll
    for (int rI = 1; rI < 16; ++rI) m = fmaxf(m, red[rI]);
    float pe = (tid < T_) ? EXP2((v - m) * LOG2E_F) : 0.f;
    float ssum = pe;
#pragma unroll
    for (int off = 32; off > 0; off >>= 1) ssum += __shfl_xor(ssum, off, 64);
    if (l == 0) red[16 + wv] = ssum;
    __syncthreads();
    float tot = 0.f;
#pragma unroll
    for (int rI = 0; rI < 16; ++rI) tot += red[16 + rI];
    float ainv = RCPF(tot);
    if (tid < T_) sm_e[tid] = pe * ainv;
    __syncthreads();
    { // c = a @ h (16 tp-splits of 16)
      const int ts = tid >> 6, c = tid & 63, n0 = c << 3;
      float a[8] = {};
      for (int tp = ts * 16; tp < ts * 16 + 16; ++tp) {
        uint4 pk = *(const uint4*)(g_hb + ((size_t)(b * T_ + tp) << 9) + n0);
        float av = sm_e[tp];
        FMA8(pk, av, a);
      }
      float* pt = smem + 1536 + ts * 512 + n0;
#pragma unroll
      for (int j = 0; j < 8; ++j) pt[j] = a[j];
    }
    __syncthreads();
    if (tid < 512) {
      float v2 = 0.f;
#pragma unroll
      for (int kk = 0; kk < 16; ++kk) v2 += smem[1536 + kk * 512 + tid];
      store_packed(b, 1024 + tid, v2);
    }
  }
}

// ---- k3: y3out (0-31) || RU (32-159) || P (160-223) — 1024 thr, 16-wave ----
__global__ void __launch_bounds__(1024) k3_y3rup(float* __restrict__ out, int t) {
  __shared__ __align__(16) float smem[16384];
  const int tid = threadIdx.x;
  const int bid = blockIdx.x;
  if (bid < 32) {
    const int mt3 = bid >> 2, nbt = bid & 3;
    gemm_w<0, 16, 1, 16, 4>(Wy3p, mt3, nbt, tid, smem);
    int row = tid >> 6, col = tid & 63;
    EPI_W(row, col, 16, 4);
    int gb = mt3 * 16 + row, gc = nbt * 64 + col;
    v += bf2f(cby3[gc]);
    out[((size_t)gb * T_ + t) * O_ + gc] = v;
  } else if (bid < 160) {
    const int idx2 = bid - 32;
    const int mt = idx2 >> 4, nbt = idx2 & 15;
    gemm_w<0, 64, 4, 16, 4>(WRUp, mt, nbt, tid, smem);
    int row = tid >> 6, col = tid & 63;
    EPI_W(row, col, 16, 4);
    int gb = mt * 16 + row, gc = nbt * 64 + col;
    v += g_bru[gc];
    if (gc < 512) {
      float rv = fsigm(v);
      float rs = rv * g_s[gb * H_ + gc];
      store_packed(gb, 2048 + gc, rs);
    } else {
      g_u[gb * H_ + (gc - 512)] = fsigm(v);
    }
  } else {
    const int idx2 = bid - 160;
    const int mt = idx2 >> 3, nbt = idx2 & 7;
    gemm_w<0, 48, 3, 16, 4>(WPp, mt, nbt, tid, smem);
    int row = tid >> 6, col = tid & 63;
    EPI_W(row, col, 16, 4);
    int gb = mt * 16 + row, gc = nbt * 64 + col;
    g_p[gb * H_ + gc] = v + g_bh[gc];
  }
}

// ---- k4: HC + s-update (128 blocks, 1024 thr, 16-wave, N=32) ----
__global__ void __launch_bounds__(1024) k4_hc() {
  __shared__ __align__(16) float smem[8192];
  const int tid = threadIdx.x;
  const int bid = blockIdx.x;
  const int mt = bid >> 4, nbt = bid & 15;
  gemm_w<64, 16, 1, 16, 2>(Whhp, mt, nbt, tid, smem);
  if (tid < 512) {
    int row = tid >> 5, col = tid & 31;
    EPI_W(row, col, 16, 2);
    int gb = mt * 16 + row, gc = nbt * 32 + col;
    int sidx = gb * H_ + gc;
    v += g_p[sidx];
    float hc = ftanh(v);
    float uu = g_u[sidx];
    float sn = (1.f - uu) * hc + uu * g_s[sidx];
    g_s[sidx] = sn;
    store_packed(gb, 1536 + gc, sn);
  }
}

extern "C" void kernel_launch(void* const* d_in, const int* in_sizes, int n_in,
                              void* d_out, int out_size, void* d_ws, size_t ws_size,
                              hipStream_t stream) {
  (void)in_sizes; (void)n_in; (void)out_size; (void)d_ws; (void)ws_size;
  const float* h = (const float*)d_in[0];
  float* out = (float*)d_out;

#define CONV(NAME, IDX, N) \
  hipLaunchKernelGGL(conv_##NAME, dim3(((N) + 255) / 256), dim3(256), 0, stream, \
                     (const float*)d_in[IDX])
  CONV(by1, 3, H_);
  CONV(by2, 5, H_);
  CONV(by3, 7, O_);
  CONV(be1, 9, H_);
  CONV(We2, 10, H_);
  // d_in[11] = be2: softmax shift-invariant, unused
#undef CONV
  // composite weights: destinations selected in device code (never pass
  // __device__ symbols as host-side kernel args — r4-r7 abort cause)
  hipLaunchKernelGGL((fgemm_comp<0>), dim3(8, 8), dim3(256), 0, stream,
                     (const float*)d_in[6], (const float*)d_in[12]);
  hipLaunchKernelGGL((fgemm_comp<1>), dim3(8, 8), dim3(256), 0, stream,
                     (const float*)d_in[6], (const float*)d_in[15]);
  hipLaunchKernelGGL((fgemm_comp<2>), dim3(8, 8), dim3(256), 0, stream,
                     (const float*)d_in[6], (const float*)d_in[18]);
  hipLaunchKernelGGL(bias_fold, dim3(6), dim3(256), 0, stream,
                     (const float*)d_in[7], (const float*)d_in[12],
                     (const float*)d_in[15], (const float*)d_in[14],
                     (const float*)d_in[17], (const float*)d_in[18]);
  hipLaunchKernelGGL(pack_Wy1, dim3(128), dim3(256), 0, stream, (const float*)d_in[2]);
  hipLaunchKernelGGL(pack_Wy2, dim3(128), dim3(256), 0, stream, (const float*)d_in[4]);
  hipLaunchKernelGGL(pack_Wy3, dim3(64), dim3(256), 0, stream, (const float*)d_in[6]);
  hipLaunchKernelGGL(pack_We1s, dim3(128), dim3(256), 0, stream, (const float*)d_in[8]);
  hipLaunchKernelGGL(pack_WRU, dim3(1024), dim3(256), 0, stream,
                     (const float*)d_in[12], (const float*)d_in[13],
                     (const float*)d_in[15], (const float*)d_in[16]);
  hipLaunchKernelGGL(pack_WP, dim3(384), dim3(256), 0, stream,
                     (const float*)d_in[18]);
  hipLaunchKernelGGL(pack_Whh, dim3(128), dim3(256), 0, stream,
                     (const float*)d_in[19]);
  hipLaunchKernelGGL(conv_h, dim3((B_ * T_ * H_) / 256), dim3(256), 0, stream, h);
  hipLaunchKernelGGL(init_kernel, dim3(256), dim3(256), 0, stream,
                     (const float*)d_in[1]);
  hipLaunchKernelGGL(hproj_kernel, dim3(8, 512), dim3(256), 0, stream, h,
                     (const float*)d_in[8]);

  for (int t = 0; t < T_; ++t) {
    hipLaunchKernelGGL(k1_y1sp, dim3(256), dim3(1024), 0, stream);
    hipLaunchKernelGGL(k2_y2attn, dim3(256), dim3(1024), 0, stream);
    hipLaunchKernelGGL(k3_y3rup, dim3(224), dim3(1024), 0, stream, out, t);
    hipLaunchKernelGGL(k4_hc, dim3(128), dim3(1024), 0, stream);
  }
}

// Round 13
// 7931.937 us; speedup vs baseline: 18.0735x; 1.0496x over previous
//
#include <hip/hip_runtime.h>

#define B_ 128
#define T_ 256
#define H_ 512
#define O_ 256
#define X_ 768

typedef unsigned short u16;
typedef unsigned int u32;

#if __has_builtin(__builtin_amdgcn_exp2f)
#define EXP2(x) __builtin_amdgcn_exp2f(x)
#else
#define EXP2(x) exp2f(x)
#endif
#if __has_builtin(__builtin_amdgcn_rcpf)
#define RCPF(x) __builtin_amdgcn_rcpf(x)
#else
#define RCPF(x) (1.0f / (x))
#endif

#define LOG2E_F 1.4426950408889634f
#define TWOLOG2E_F 2.8853900817779268f

typedef __attribute__((ext_vector_type(8))) short short8;
typedef __attribute__((ext_vector_type(4))) float f32x4;

__device__ __forceinline__ float bf2f(u16 v) {
  union { u32 u; float f; } c; c.u = ((u32)v) << 16; return c.f;
}
__device__ __forceinline__ u16 f2bf(float f) {
  union { float f; u32 u; } c; c.f = f;
  return (u16)((c.u + 0x7FFFu + ((c.u >> 16) & 1u)) >> 16);
}
__device__ __forceinline__ float ftanh(float x) {
  x = fminf(fmaxf(x, -40.f), 40.f);
  float z = EXP2(x * TWOLOG2E_F);
  return (z - 1.0f) * RCPF(z + 1.0f);
}
__device__ __forceinline__ float fsigm(float x) {
  x = fminf(fmaxf(x, -40.f), 40.f);
  return RCPF(1.0f + EXP2(-x * LOG2E_F));
}

// ---- module-scope scratch ----
__device__ u16 g_hp[(size_t)B_ * T_ * H_];   // bf16 h_proj
__device__ u16 g_hb[(size_t)B_ * T_ * H_];   // bf16 copy of h
__device__ float g_s[B_ * H_];               // fp32 state
__device__ float g_u[B_ * H_];
__device__ float g_sp[B_ * H_];              // s @ We1_s + be1
__device__ float g_p[B_ * H_];               // [y2,c] @ WP (+bh fold)

// composite-weight scratch (fp32, one-time)
__device__ float g_wcru[512 * 1024];         // Wy3 @ [Wxr_top | Wxu_top]
__device__ float g_wch[512 * 512];           // Wy3 @ Wxh_top
__device__ float g_bru[1024];                // br|bu + by3 @ Wx_top
__device__ float g_bh[512];                  // by3 @ Wxh_top

// Fragment-packed activation A buffer (bf16 hi + lo residual), NKT=96 k-tiles.
// col slabs: [0,512)=y2 (kt0-15), [512,1024)=c (kt16-31), [1024,1536)=s
// (kt32-47), [1536,2048)=r*s (kt48-63), [2048,2560)=y1 (kt64-79)
// idx = ((rt*96 + kt)*512) + ((kg*16 + r)*8) + j ; rt=b>>4, r=b&15,
// kt=col>>5, kg=(col>>3)&3, j=col&7
__device__ u16 g_ah[(size_t)8 * 96 * 512];
__device__ u16 g_al[(size_t)8 * 96 * 512];

// Fragment-packed bf16 weights: idx = ((ntile*NKT + kt)*512 + l*8 + j)
__device__ u16 Wy1p[(size_t)32 * 16 * 512];
__device__ u16 Wy2p[(size_t)32 * 16 * 512];
__device__ u16 Wy3p[(size_t)16 * 16 * 512];
__device__ u16 We1sp[(size_t)32 * 16 * 512];
// WRUp: N=1024 (r|u), K=1536: kt0-15=Wc(single bf16), 16-31=Wx_mid, 32-47=Wh
__device__ u16 WRUp[(size_t)64 * 48 * 512];
// WPp: N=512, K=1024: kt0-15=Wch(single), 16-31=Wxh_mid
__device__ u16 WPp[(size_t)32 * 32 * 512];
// Whhp: N=512, K=512
__device__ u16 Whhp[(size_t)32 * 16 * 512];

__device__ u16 cby1[H_];
__device__ u16 cby2[H_];
__device__ u16 cby3[O_];
__device__ u16 cbe1[H_];
__device__ u16 cWe2[H_];

__device__ __forceinline__ void store_packed(int b, int col, float v) {
  u16 hi = f2bf(v);
  size_t idx = (((size_t)(b >> 4) * 96 + (col >> 5)) << 9) +
               ((((col >> 3) & 3) * 16 + (b & 15)) << 3) + (col & 7);
  g_ah[idx] = hi;
  g_al[idx] = f2bf(v - bf2f(hi));
}

#define DEF_CONV(NAME, ARR, N)                                     \
  __global__ void conv_##NAME(const float* __restrict__ s) {       \
    int i = blockIdx.x * 256 + threadIdx.x;                        \
    if (i < (N)) ARR[i] = f2bf(s[i]);                              \
  }

DEF_CONV(by1, cby1, H_)
DEF_CONV(by2, cby2, H_)
DEF_CONV(by3, cby3, O_)
DEF_CONV(be1, cbe1, H_)
DEF_CONV(We2, cWe2, H_)

__global__ void conv_h(const float* __restrict__ s) {
  size_t i = (size_t)blockIdx.x * 256 + threadIdx.x;
  g_hb[i] = f2bf(s[i]);
}

// ---- composite GEMM: C[MODE] = A(512x256,lda256) @ B(256x512,ldb512) ----
// MODE selects the __device__ destination INSIDE device code (host code must
// never take the address of a __device__ symbol — that was the r4-r7 abort).
template <int MODE>
__global__ void __launch_bounds__(256) fgemm_comp(const float* __restrict__ A,
                                                  const float* __restrict__ B) {
  float* C = (MODE == 0) ? g_wcru : (MODE == 1) ? (g_wcru + 512) : g_wch;
  const int ldc = (MODE == 2) ? 512 : 1024;
  __shared__ float Ast[32][72];
  __shared__ float Bs[32][72];
  const int tid = threadIdx.x;
  const int tx = tid & 15, ty = tid >> 4;
  const int n0 = blockIdx.x << 6;
  const int m0 = blockIdx.y << 6;
  float acc[4][4] = {};
  for (int k0 = 0; k0 < 256; k0 += 32) {
    {
      int row = tid >> 2, kq = (tid & 3) << 3;
      const float* src = A + (size_t)(m0 + row) * 256 + k0 + kq;
      float4 v0 = *(const float4*)src;
      float4 v1 = *(const float4*)(src + 4);
      Ast[kq + 0][row] = v0.x; Ast[kq + 1][row] = v0.y;
      Ast[kq + 2][row] = v0.z; Ast[kq + 3][row] = v0.w;
      Ast[kq + 4][row] = v1.x; Ast[kq + 5][row] = v1.y;
      Ast[kq + 6][row] = v1.z; Ast[kq + 7][row] = v1.w;
    }
    {
      int kr = tid >> 3, nq = (tid & 7) << 3;
      const float* src = B + (size_t)(k0 + kr) * 512 + n0 + nq;
      float4 v0 = *(const float4*)src;
      float4 v1 = *(const float4*)(src + 4);
      float* d = &Bs[kr][nq];
      d[0] = v0.x; d[1] = v0.y; d[2] = v0.z; d[3] = v0.w;
      d[4] = v1.x; d[5] = v1.y; d[6] = v1.z; d[7] = v1.w;
    }
    __syncthreads();
#pragma unroll
    for (int kk = 0; kk < 32; ++kk) {
      const float4 a4 = *(const float4*)&Ast[kk][ty << 2];
      const float4 b4 = *(const float4*)&Bs[kk][tx << 2];
      float av[4] = {a4.x, a4.y, a4.z, a4.w};
      float bv[4] = {b4.x, b4.y, b4.z, b4.w};
#pragma unroll
      for (int i = 0; i < 4; ++i)
#pragma unroll
        for (int j = 0; j < 4; ++j) acc[i][j] = fmaf(av[i], bv[j], acc[i][j]);
    }
    __syncthreads();
  }
#pragma unroll
  for (int i = 0; i < 4; ++i)
#pragma unroll
    for (int j = 0; j < 4; ++j)
      C[(size_t)(m0 + ty * 4 + i) * ldc + n0 + tx * 4 + j] = acc[i][j];
}

__global__ void bias_fold(const float* __restrict__ by3,
                          const float* __restrict__ Wxr,
                          const float* __restrict__ Wxu,
                          const float* __restrict__ br,
                          const float* __restrict__ bu,
                          const float* __restrict__ Wxh) {
  int n = blockIdx.x * 256 + threadIdx.x;
  if (n < 1024) {
    const float* W = (n < 512) ? Wxr : Wxu;
    int nn = n & 511;
    float acc = (n < 512) ? br[nn] : bu[nn];
    for (int k = 0; k < 256; ++k) acc += by3[k] * W[(size_t)k * 512 + nn];
    g_bru[n] = acc;
  } else if (n < 1536) {
    int nn = n - 1024;
    float acc = 0.f;
    for (int k = 0; k < 256; ++k) acc += by3[k] * Wxh[(size_t)k * 512 + nn];
    g_bh[nn] = acc;
  }
}

// ---- weight packers ----
#define DEF_PACKB(NAME, DST, NKT, SRCEXPR)                               \
  __global__ void NAME(const float* __restrict__ S0) {                   \
    int gid = blockIdx.x * 256 + threadIdx.x;                            \
    int l = gid & 63, kt = (gid >> 6) % (NKT);                           \
    int ntile = gid / (64 * (NKT));                                      \
    int n = ntile * 16 + (l & 15);                                       \
    __align__(16) u16 tmp[8];                                            \
    _Pragma("unroll")                                                    \
    for (int j = 0; j < 8; ++j) {                                        \
      int k = kt * 32 + ((l >> 4) << 3) + j;                             \
      tmp[j] = f2bf(SRCEXPR);                                            \
    }                                                                    \
    *(uint4*)(DST + (size_t)gid * 8) = *(const uint4*)tmp;               \
  }

DEF_PACKB(pack_Wy1, Wy1p, 16, S0[(size_t)k * 512 + n])
DEF_PACKB(pack_Wy2, Wy2p, 16, S0[(size_t)k * 512 + n])
DEF_PACKB(pack_Wy3, Wy3p, 16, S0[(size_t)k * 256 + n])
DEF_PACKB(pack_We1s, We1sp, 16, S0[(size_t)(512 + k) * 512 + n])

__global__ void pack_WRU(const float* __restrict__ Wxr, const float* __restrict__ Whr,
                         const float* __restrict__ Wxu, const float* __restrict__ Whu) {
  int gid = blockIdx.x * 256 + threadIdx.x;   // 64 ntile * 48 kt * 64 lanes
  int l = gid & 63, kt = (gid >> 6) % 48;
  int ntile = gid / (64 * 48);
  int n = ntile * 16 + (l & 15);
  int nn = n & 511;
  __align__(16) u16 tmp[8];
#pragma unroll
  for (int j = 0; j < 8; ++j) {
    int k = kt * 32 + ((l >> 4) << 3) + j;   // 0..1535
    float v;
    if (k < 512) v = g_wcru[(size_t)k * 1024 + n];
    else if (k < 1024) {
      v = (n < 512) ? Wxr[(size_t)(k - 512 + 256) * 512 + nn]
                    : Wxu[(size_t)(k - 512 + 256) * 512 + nn];
    } else {
      v = (n < 512) ? Whr[(size_t)(k - 1024) * 512 + nn]
                    : Whu[(size_t)(k - 1024) * 512 + nn];
    }
    tmp[j] = f2bf(v);
  }
  *(uint4*)(WRUp + (size_t)gid * 8) = *(const uint4*)tmp;
}

__global__ void pack_WP(const float* __restrict__ Wxh) {
  int gid = blockIdx.x * 256 + threadIdx.x;   // 32 ntile * 32 kt * 64 lanes
  int l = gid & 63, kt = (gid >> 6) & 31;
  int ntile = gid >> 11;
  int n = ntile * 16 + (l & 15);
  __align__(16) u16 tmp[8];
#pragma unroll
  for (int j = 0; j < 8; ++j) {
    int k = kt * 32 + ((l >> 4) << 3) + j;   // 0..1023
    float v;
    if (k < 512) v = g_wch[(size_t)k * 512 + n];
    else v = Wxh[(size_t)(k - 512 + 256) * 512 + n];
    tmp[j] = f2bf(v);
  }
  *(uint4*)(WPp + (size_t)gid * 8) = *(const uint4*)tmp;
}

__global__ void pack_Whh(const float* __restrict__ Whh) {
  int gid = blockIdx.x * 256 + threadIdx.x;   // 32 ntile * 16 kt * 64 lanes
  int l = gid & 63, kt = (gid >> 6) & 15;
  int ntile = gid >> 10;
  int n = ntile * 16 + (l & 15);
  __align__(16) u16 tmp[8];
#pragma unroll
  for (int j = 0; j < 8; ++j) {
    int k = kt * 32 + ((l >> 4) << 3) + j;
    tmp[j] = f2bf(Whh[(size_t)k * 512 + n]);
  }
  *(uint4*)(Whhp + (size_t)gid * 8) = *(const uint4*)tmp;
}

__global__ void init_kernel(const float* __restrict__ s0) {
  int g = blockIdx.x * blockDim.x + threadIdx.x;
  if (g < B_ * H_) {
    float v = s0[g];
    g_s[g] = v;
    int b = g >> 9, n = g & 511;
    store_packed(b, 1024 + n, v);   // s slab @ kt32
  }
}

// ---- h_proj = h @ We1[:H]  (fp32 in, bf16 out) ----
__global__ void __launch_bounds__(256) hproj_kernel(const float* __restrict__ hh,
                                                    const float* __restrict__ We1) {
  __shared__ float Ast[32][72];
  __shared__ float Bs[32][72];
  const int tid = threadIdx.x;
  const int tx = tid & 15, ty = tid >> 4;
  const int n0 = blockIdx.x << 6;
  const int m0 = blockIdx.y << 6;
  float acc[4][4] = {};
  for (int k0 = 0; k0 < H_; k0 += 32) {
    {
      int row = tid >> 2, kq = (tid & 3) << 3;
      const float* src = hh + (size_t)(m0 + row) * H_ + k0 + kq;
      float4 v0 = *(const float4*)src;
      float4 v1 = *(const float4*)(src + 4);
      Ast[kq + 0][row] = v0.x; Ast[kq + 1][row] = v0.y;
      Ast[kq + 2][row] = v0.z; Ast[kq + 3][row] = v0.w;
      Ast[kq + 4][row] = v1.x; Ast[kq + 5][row] = v1.y;
      Ast[kq + 6][row] = v1.z; Ast[kq + 7][row] = v1.w;
    }
    {
      int kr = tid >> 3, nq = (tid & 7) << 3;
      const float* src = We1 + (size_t)(k0 + kr) * H_ + n0 + nq;
      float4 v0 = *(const float4*)src;
      float4 v1 = *(const float4*)(src + 4);
      float* d = &Bs[kr][nq];
      d[0] = v0.x; d[1] = v0.y; d[2] = v0.z; d[3] = v0.w;
      d[4] = v1.x; d[5] = v1.y; d[6] = v1.z; d[7] = v1.w;
    }
    __syncthreads();
#pragma unroll
    for (int kk = 0; kk < 32; ++kk) {
      const float4 a4 = *(const float4*)&Ast[kk][ty << 2];
      const float4 b4 = *(const float4*)&Bs[kk][tx << 2];
      float av[4] = {a4.x, a4.y, a4.z, a4.w};
      float bv[4] = {b4.x, b4.y, b4.z, b4.w};
#pragma unroll
      for (int i = 0; i < 4; ++i)
#pragma unroll
        for (int j = 0; j < 4; ++j) acc[i][j] = fmaf(av[i], bv[j], acc[i][j]);
    }
    __syncthreads();
  }
#pragma unroll
  for (int i = 0; i < 4; ++i) {
    u16* dst = g_hp + (size_t)(m0 + ty * 4 + i) * H_ + n0 + tx * 4;
    u32 w0 = (u32)f2bf(acc[i][0]) | ((u32)f2bf(acc[i][1]) << 16);
    u32 w1 = (u32)f2bf(acc[i][2]) | ((u32)f2bf(acc[i][3]) << 16);
    *(u32*)dst = w0;
    *(u32*)(dst + 2) = w1;
  }
}

#define FMA8(pk, sk, A)                                          \
  {                                                              \
    u32 ww0 = pk.x, ww1 = pk.y, ww2 = pk.z, ww3 = pk.w;          \
    A[0] = fmaf(sk, bf2f((u16)(ww0 & 0xffffu)), A[0]);           \
    A[1] = fmaf(sk, bf2f((u16)(ww0 >> 16)), A[1]);               \
    A[2] = fmaf(sk, bf2f((u16)(ww1 & 0xffffu)), A[2]);           \
    A[3] = fmaf(sk, bf2f((u16)(ww1 >> 16)), A[3]);               \
    A[4] = fmaf(sk, bf2f((u16)(ww2 & 0xffffu)), A[4]);           \
    A[5] = fmaf(sk, bf2f((u16)(ww2 >> 16)), A[5]);               \
    A[6] = fmaf(sk, bf2f((u16)(ww3 & 0xffffu)), A[6]);           \
    A[7] = fmaf(sk, bf2f((u16)(ww3 >> 16)), A[7]);               \
  }

// ---- generalized GEMM core: M=16, N=NT*16, NW waves k-split, hi/lo A ----
template <int KTA0, int NKT_B, int KTW, int NW, int NT>
__device__ __forceinline__ void gemm_w(const u16* __restrict__ BP, int mt,
                                       int nbt, int tid, float* smem) {
  const int l = tid & 63, w = tid >> 6;   // w in [0, NW)
  f32x4 acc[NT];
#pragma unroll
  for (int nt = 0; nt < NT; ++nt) acc[nt] = (f32x4){0.f, 0.f, 0.f, 0.f};
  const size_t abase = (((size_t)mt * 96 + KTA0 + w * KTW) << 9) + l * 8;
#pragma unroll
  for (int kk = 0; kk < KTW; ++kk) {
    short8 ah = *(const short8*)(g_ah + abase + (size_t)kk * 512);
    short8 al = *(const short8*)(g_al + abase + (size_t)kk * 512);
    const size_t bbase =
        (((size_t)(nbt * NT) * NKT_B + w * KTW + kk) << 9) + l * 8;
#pragma unroll
    for (int nt = 0; nt < NT; ++nt) {
      short8 bb = *(const short8*)(BP + bbase + (((size_t)nt * NKT_B) << 9));
      acc[nt] = __builtin_amdgcn_mfma_f32_16x16x32_bf16(ah, bb, acc[nt], 0, 0, 0);
      acc[nt] = __builtin_amdgcn_mfma_f32_16x16x32_bf16(al, bb, acc[nt], 0, 0, 0);
    }
  }
  float* pw = smem + w * (NT * 256);
  const int r0 = (l >> 4) * 4, c0 = l & 15;
#pragma unroll
  for (int r = 0; r < 4; ++r)
#pragma unroll
    for (int nt = 0; nt < NT; ++nt)
      pw[(r0 + r) * (NT * 16) + nt * 16 + c0] = acc[nt][r];
  __syncthreads();
}

#define EPI_W(row, col, NW, NT)                                      \
  float v = 0.f;                                                     \
  _Pragma("unroll") for (int ww = 0; ww < (NW); ++ww)                \
      v += smem[ww * ((NT) * 256) + (row) * ((NT) * 16) + (col)];

// ---- k1: y1 (0-127) || sp (128-255) — 1024 thr, 16-wave, N=32 ----
__global__ void __launch_bounds__(1024) k1_y1sp() {
  __shared__ __align__(16) float smem[8192];
  const int tid = threadIdx.x;
  const int bid = blockIdx.x;
  if (bid < 128) {
    const int mt = bid >> 4, nbt = bid & 15;
    gemm_w<32, 16, 1, 16, 2>(Wy1p, mt, nbt, tid, smem);
    if (tid < 512) {
      int row = tid >> 5, col = tid & 31;
      EPI_W(row, col, 16, 2);
      int gb = mt * 16 + row, gc = nbt * 32 + col;
      v += bf2f(cby1[gc]);
      store_packed(gb, 2048 + gc, ftanh(v));   // y1 slab @ kt64
    }
  } else {
    const int blk2 = bid - 128;
    const int mt = blk2 >> 4, nbt = blk2 & 15;
    gemm_w<32, 16, 1, 16, 2>(We1sp, mt, nbt, tid, smem);
    if (tid < 512) {
      int row = tid >> 5, col = tid & 31;
      EPI_W(row, col, 16, 2);
      int gb = mt * 16 + row, gc = nbt * 32 + col;
      g_sp[gb * H_ + gc] = v + bf2f(cbe1[gc]);
    }
  }
}

// ---- k2: y2 (0-127, 16-wave N=32) || attn (128-255, 1024 thr) ----
__global__ void __launch_bounds__(1024) k2_y2attn() {
  __shared__ __align__(16) float smem[10240];
  __shared__ float red[32];
  const int tid = threadIdx.x;
  const int bid = blockIdx.x;
  if (bid < 128) {
    const int mt = bid >> 4, nbt = bid & 15;
    gemm_w<64, 16, 1, 16, 2>(Wy2p, mt, nbt, tid, smem);
    if (tid < 512) {
      int row = tid >> 5, col = tid & 31;
      EPI_W(row, col, 16, 2);
      int gb = mt * 16 + row, gc = nbt * 32 + col;
      v += bf2f(cby2[gc]);
      store_packed(gb, gc, ftanh(v));          // y2 slab @ kt0 (no dup)
    }
  } else {
    const int b = bid - 128;
    float* sm_e = smem + 1024;
    if (tid < 512) {
      float spv = g_sp[b * H_ + tid];
      float w2 = bf2f(cWe2[tid]);
      smem[2 * tid] = spv * TWOLOG2E_F;
      smem[2 * tid + 1] = -2.0f * w2;
    }
    __syncthreads();
    const int wv = tid >> 6, l = tid & 63;   // 16 waves
    const int rr = l & 15, q = l >> 4;
    {
      int tp = wv * 16 + rr;                 // one pass covers all 256 tp
      const u16* rowp = g_hp + ((size_t)(b * T_ + tp) << 9);
      float part = 0.f;
      for (int i = 0; i < 16; ++i) {
        int c0 = i * 32 + q * 8;
        uint4 pk = *(const uint4*)(rowp + c0);
        const float4* swp = reinterpret_cast<const float4*>(smem + 2 * c0);
        float4 f0 = swp[0], f1 = swp[1], f2 = swp[2], f3 = swp[3];
        u32 ww[4] = {pk.x, pk.y, pk.z, pk.w};
        {
          float h0 = bf2f((u16)(ww[0] & 0xffffu)), h1 = bf2f((u16)(ww[0] >> 16));
          float x0 = fmaf(h0, TWOLOG2E_F, f0.x);
          float x1 = fmaf(h1, TWOLOG2E_F, f0.z);
          part = fmaf(f0.y, RCPF(EXP2(x0) + 1.f), part);
          part = fmaf(f0.w, RCPF(EXP2(x1) + 1.f), part);
        }
        {
          float h0 = bf2f((u16)(ww[1] & 0xffffu)), h1 = bf2f((u16)(ww[1] >> 16));
          float x0 = fmaf(h0, TWOLOG2E_F, f1.x);
          float x1 = fmaf(h1, TWOLOG2E_F, f1.z);
          part = fmaf(f1.y, RCPF(EXP2(x0) + 1.f), part);
          part = fmaf(f1.w, RCPF(EXP2(x1) + 1.f), part);
        }
        {
          float h0 = bf2f((u16)(ww[2] & 0xffffu)), h1 = bf2f((u16)(ww[2] >> 16));
          float x0 = fmaf(h0, TWOLOG2E_F, f2.x);
          float x1 = fmaf(h1, TWOLOG2E_F, f2.z);
          part = fmaf(f2.y, RCPF(EXP2(x0) + 1.f), part);
          part = fmaf(f2.w, RCPF(EXP2(x1) + 1.f), part);
        }
        {
          float h0 = bf2f((u16)(ww[3] & 0xffffu)), h1 = bf2f((u16)(ww[3] >> 16));
          float x0 = fmaf(h0, TWOLOG2E_F, f3.x);
          float x1 = fmaf(h1, TWOLOG2E_F, f3.z);
          part = fmaf(f3.y, RCPF(EXP2(x0) + 1.f), part);
          part = fmaf(f3.w, RCPF(EXP2(x1) + 1.f), part);
        }
      }
      part += __shfl_xor(part, 16, 64);
      part += __shfl_xor(part, 32, 64);
      if (q == 0) sm_e[tp] = part;
    }
    __syncthreads();
    float v = (tid < T_) ? sm_e[tid] : -3.0e38f;
    float m = v;
#pragma unroll
    for (int off = 32; off > 0; off >>= 1) m = fmaxf(m, __shfl_xor(m, off, 64));
    if (l == 0) red[wv] = m;
    __syncthreads();
    m = red[0];
#pragma unroll
    for (int rI = 1; rI < 16; ++rI) m = fmaxf(m, red[rI]);
    float pe = (tid < T_) ? EXP2((v - m) * LOG2E_F) : 0.f;
    float ssum = pe;
#pragma unroll
    for (int off = 32; off > 0; off >>= 1) ssum += __shfl_xor(ssum, off, 64);
    if (l == 0) red[16 + wv] = ssum;
    __syncthreads();
    float tot = 0.f;
#pragma unroll
    for (int rI = 0; rI < 16; ++rI) tot += red[16 + rI];
    float ainv = RCPF(tot);
    if (tid < T_) sm_e[tid] = pe * ainv;
    __syncthreads();
    { // c = a @ h (16 tp-splits of 16)
      const int ts = tid >> 6, c = tid & 63, n0 = c << 3;
      float a[8] = {};
      for (int tp = ts * 16; tp < ts * 16 + 16; ++tp) {
        uint4 pk = *(const uint4*)(g_hb + ((size_t)(b * T_ + tp) << 9) + n0);
        float av = sm_e[tp];
        FMA8(pk, av, a);
      }
      float* pt = smem + 1536 + ts * 512 + n0;
#pragma unroll
      for (int j = 0; j < 8; ++j) pt[j] = a[j];
    }
    __syncthreads();
    if (tid < 512) {
      float v2 = 0.f;
#pragma unroll
      for (int kk = 0; kk < 16; ++kk) v2 += smem[1536 + kk * 512 + tid];
      store_packed(b, 512 + tid, v2);          // c slab @ kt16
    }
  }
}

// ---- k3: y3out (0-31) || RU (32-159) || P (160-223) — 1024 thr, 16-wave ----
__global__ void __launch_bounds__(1024) k3_y3rup(float* __restrict__ out, int t) {
  __shared__ __align__(16) float smem[16384];
  const int tid = threadIdx.x;
  const int bid = blockIdx.x;
  if (bid < 32) {
    const int mt3 = bid >> 2, nbt = bid & 3;
    gemm_w<0, 16, 1, 16, 4>(Wy3p, mt3, nbt, tid, smem);
    int row = tid >> 6, col = tid & 63;
    EPI_W(row, col, 16, 4);
    int gb = mt3 * 16 + row, gc = nbt * 64 + col;
    v += bf2f(cby3[gc]);
    out[((size_t)gb * T_ + t) * O_ + gc] = v;
  } else if (bid < 160) {
    const int idx2 = bid - 32;
    const int mt = idx2 >> 4, nbt = idx2 & 15;
    gemm_w<0, 48, 3, 16, 4>(WRUp, mt, nbt, tid, smem);
    int row = tid >> 6, col = tid & 63;
    EPI_W(row, col, 16, 4);
    int gb = mt * 16 + row, gc = nbt * 64 + col;
    v += g_bru[gc];
    if (gc < 512) {
      float rv = fsigm(v);
      float rs = rv * g_s[gb * H_ + gc];
      store_packed(gb, 1536 + gc, rs);         // rs slab @ kt48
    } else {
      g_u[gb * H_ + (gc - 512)] = fsigm(v);
    }
  } else {
    const int idx2 = bid - 160;
    const int mt = idx2 >> 3, nbt = idx2 & 7;
    gemm_w<0, 32, 2, 16, 4>(WPp, mt, nbt, tid, smem);
    int row = tid >> 6, col = tid & 63;
    EPI_W(row, col, 16, 4);
    int gb = mt * 16 + row, gc = nbt * 64 + col;
    g_p[gb * H_ + gc] = v + g_bh[gc];
  }
}

// ---- k4: HC + s-update (128 blocks, 1024 thr, 16-wave, N=32) ----
__global__ void __launch_bounds__(1024) k4_hc() {
  __shared__ __align__(16) float smem[8192];
  const int tid = threadIdx.x;
  const int bid = blockIdx.x;
  const int mt = bid >> 4, nbt = bid & 15;
  gemm_w<48, 16, 1, 16, 2>(Whhp, mt, nbt, tid, smem);
  if (tid < 512) {
    int row = tid >> 5, col = tid & 31;
    EPI_W(row, col, 16, 2);
    int gb = mt * 16 + row, gc = nbt * 32 + col;
    int sidx = gb * H_ + gc;
    v += g_p[sidx];
    float hc = ftanh(v);
    float uu = g_u[sidx];
    float sn = (1.f - uu) * hc + uu * g_s[sidx];
    g_s[sidx] = sn;
    store_packed(gb, 1024 + gc, sn);           // s slab @ kt32
  }
}

extern "C" void kernel_launch(void* const* d_in, const int* in_sizes, int n_in,
                              void* d_out, int out_size, void* d_ws, size_t ws_size,
                              hipStream_t stream) {
  (void)in_sizes; (void)n_in; (void)out_size; (void)d_ws; (void)ws_size;
  const float* h = (const float*)d_in[0];
  float* out = (float*)d_out;

#define CONV(NAME, IDX, N) \
  hipLaunchKernelGGL(conv_##NAME, dim3(((N) + 255) / 256), dim3(256), 0, stream, \
                     (const float*)d_in[IDX])
  CONV(by1, 3, H_);
  CONV(by2, 5, H_);
  CONV(by3, 7, O_);
  CONV(be1, 9, H_);
  CONV(We2, 10, H_);
  // d_in[11] = be2: softmax shift-invariant, unused
#undef CONV
  // composite weights: destinations selected in device code (never pass
  // __device__ symbols as host-side kernel args — r4-r7 abort cause)
  hipLaunchKernelGGL((fgemm_comp<0>), dim3(8, 8), dim3(256), 0, stream,
                     (const float*)d_in[6], (const float*)d_in[12]);
  hipLaunchKernelGGL((fgemm_comp<1>), dim3(8, 8), dim3(256), 0, stream,
                     (const float*)d_in[6], (const float*)d_in[15]);
  hipLaunchKernelGGL((fgemm_comp<2>), dim3(8, 8), dim3(256), 0, stream,
                     (const float*)d_in[6], (const float*)d_in[18]);
  hipLaunchKernelGGL(bias_fold, dim3(6), dim3(256), 0, stream,
                     (const float*)d_in[7], (const float*)d_in[12],
                     (const float*)d_in[15], (const float*)d_in[14],
                     (const float*)d_in[17], (const float*)d_in[18]);
  hipLaunchKernelGGL(pack_Wy1, dim3(128), dim3(256), 0, stream, (const float*)d_in[2]);
  hipLaunchKernelGGL(pack_Wy2, dim3(128), dim3(256), 0, stream, (const float*)d_in[4]);
  hipLaunchKernelGGL(pack_Wy3, dim3(64), dim3(256), 0, stream, (const float*)d_in[6]);
  hipLaunchKernelGGL(pack_We1s, dim3(128), dim3(256), 0, stream, (const float*)d_in[8]);
  hipLaunchKernelGGL(pack_WRU, dim3(768), dim3(256), 0, stream,
                     (const float*)d_in[12], (const float*)d_in[13],
                     (const float*)d_in[15], (const float*)d_in[16]);
  hipLaunchKernelGGL(pack_WP, dim3(256), dim3(256), 0, stream,
                     (const float*)d_in[18]);
  hipLaunchKernelGGL(pack_Whh, dim3(128), dim3(256), 0, stream,
                     (const float*)d_in[19]);
  hipLaunchKernelGGL(conv_h, dim3((B_ * T_ * H_) / 256), dim3(256), 0, stream, h);
  hipLaunchKernelGGL(init_kernel, dim3(256), dim3(256), 0, stream,
                     (const float*)d_in[1]);
  hipLaunchKernelGGL(hproj_kernel, dim3(8, 512), dim3(256), 0, stream, h,
                     (const float*)d_in[8]);

  for (int t = 0; t < T_; ++t) {
    hipLaunchKernelGGL(k1_y1sp, dim3(256), dim3(1024), 0, stream);
    hipLaunchKernelGGL(k2_y2attn, dim3(256), dim3(1024), 0, stream);
    hipLaunchKernelGGL(k3_y3rup, dim3(224), dim3(1024), 0, stream, out, t);
    hipLaunchKernelGGL(k4_hc, dim3(128), dim3(1024), 0, stream);
  }
}